// Round 3
// baseline (994.115 us; speedup 1.0000x reference)
//
#include <hip/hip_runtime.h>
#include <math.h>

#define THW 65536
#define HW  4096
#define C96 96
#ifndef M_PI
#define M_PI 3.14159265358979323846
#endif

// ---------------- basis init (once per launch; ws is re-poisoned each call) --
__global__ __launch_bounds__(256) void init_basis_k(float* __restrict__ b64,
                                                    float* __restrict__ b16) {
  int tid = threadIdx.x;
  for (int i = tid; i < 4096; i += 256) {
    int n = i >> 6, x = i & 63;
    double s = sqrt(2.0 / 64.0) * (n == 0 ? sqrt(0.5) : 1.0);
    b64[i] = (float)(cos((double)n * ((double)x + 0.5) * M_PI / 64.0) * s);
  }
  {
    int n = tid >> 4, x = tid & 15;
    double s = sqrt(2.0 / 16.0) * (n == 0 ? sqrt(0.5) : 1.0);
    b16[tid & 255] = (float)(cos((double)n * ((double)x + 0.5) * M_PI / 16.0) * s);
  }
}

// ---------------- depthwise 3x3x3 conv: LDS planes + sliding h-window --------
// block: one (b*c), t-slab of 2. LDS: 4 planes of 66 rows x 72 cols (zero pad).
// thread: (s=w-strip of 8, tc=t-center 0/1, seg=h-segment of 4), slides 3-row
// register window along h: 3 LDS row-loads per 8 outputs, 216 FMA.
__global__ __launch_bounds__(256, 2) void dwconv_k(const float* __restrict__ x,
    const float* __restrict__ wv, const float* __restrict__ bias,
    float* __restrict__ y) {
  __shared__ float lds[4 * 66 * 72];  // 76 KB
  int tid = threadIdx.x;
  int t0 = blockIdx.x * 2;
  int bc = blockIdx.y;
  int c  = bc % C96;
  const float* xp = x + (size_t)bc * THW;

  // zero whole tile (covers halo)
  float4 z4 = make_float4(0.f, 0.f, 0.f, 0.f);
  for (int i = tid; i < 4752; i += 256) ((float4*)lds)[i] = z4;
  __syncthreads();
  // stage 4 planes t0-1 .. t0+2 (interior at rows 1..64, cols 4..67)
  for (int p = 0; p < 4; ++p) {
    int tt = t0 - 1 + p;
    if (tt < 0 || tt > 15) continue;
    const float* pp = xp + tt * HW;
    for (int i = tid; i < 1024; i += 256) {
      int row = i >> 4, c4 = i & 15;
      float4 v = *(const float4*)(pp + row * 64 + c4 * 4);
      *(float4*)&lds[(p * 66 + row + 1) * 72 + 4 + c4 * 4] = v;
    }
  }
  float w27[27];
#pragma unroll
  for (int i = 0; i < 27; ++i) w27[i] = wv[c * 27 + i];
  float bv = bias[c];
  __syncthreads();

  int s   = tid & 7;          // w-strip: cols s*8 .. s*8+7
  int tc  = (tid >> 3) & 1;   // t-center t0+tc
  int seg = tid >> 4;         // h-segment: rows seg*4 .. +3
  int h0 = seg * 4;
  int cb = 3 + 8 * s;         // lds col of (w-1)

  float win[3][3][10];
#define LOADROW(q, slot, ldsrow) { \
    const float* rp = &lds[(((tc) + (q)) * 66 + (ldsrow)) * 72 + cb]; \
    _Pragma("unroll") for (int j = 0; j < 10; ++j) win[q][slot][j] = rp[j]; }

#pragma unroll
  for (int q = 0; q < 3; ++q) { LOADROW(q, 0, h0); LOADROW(q, 1, h0 + 1); }

  float* yp = y + (size_t)bc * THW + (t0 + tc) * HW + s * 8;
#pragma unroll
  for (int st = 0; st < 4; ++st) {
    int h = h0 + st;
#pragma unroll
    for (int q = 0; q < 3; ++q) { LOADROW(q, (st + 2) % 3, h + 2); }
    float acc[8];
#pragma unroll
    for (int w = 0; w < 8; ++w) acc[w] = bv;
#pragma unroll
    for (int q = 0; q < 3; ++q)
#pragma unroll
      for (int rr = 0; rr < 3; ++rr) {
        const float* row = win[q][(st + rr) % 3];
#pragma unroll
        for (int dw = 0; dw < 3; ++dw) {
          float coef = w27[q * 9 + rr * 3 + dw];
#pragma unroll
          for (int w = 0; w < 8; ++w) acc[w] = fmaf(row[w + dw], coef, acc[w]);
        }
      }
    *(float4*)&yp[h * 64]     = make_float4(acc[0], acc[1], acc[2], acc[3]);
    *(float4*)&yp[h * 64 + 4] = make_float4(acc[4], acc[5], acc[6], acc[7]);
  }
#undef LOADROW
}

// ---------------- fe transpose: [THW][96] -> [96][THW] -----------------------
__global__ __launch_bounds__(256) void feT_k(const float* __restrict__ fe,
                                             float* __restrict__ feT) {
  __shared__ float t[96 * 65];
  int tid = threadIdx.x;
  int tok0 = blockIdx.x * 64;
  const float* p = fe + (size_t)tok0 * 96;
  for (int i = tid; i < 6144; i += 256) {
    int tok = i / 96;
    int ch = i - tok * 96;
    t[ch * 65 + tok] = p[i];
  }
  __syncthreads();
  for (int i = tid; i < 6144; i += 256) {
    int ch = i >> 6, tok = i & 63;
    feT[(size_t)ch * THW + tok0 + tok] = t[ch * 65 + tok];
  }
}

// ---------------- LDS-staged, pipelined 96xN GEMM family ---------------------
// Out[co][n] = sum_k W[co][k] * In[k][n]  (+ epilogue)
// EPI 0: + bias, plain store
// EPI 1: tau: t=acc; tau=gelu(t); write A,B spectral maps
// EPI 2: LN+SiLU-gate applied to In (and z) inside the k-loop
#define FMA4(A, WV) \
  A.x = fmaf(WV, v.x, A.x); A.y = fmaf(WV, v.y, A.y); \
  A.z = fmaf(WV, v.z, A.z); A.w = fmaf(WV, v.w, A.w);

template <int EPI, int BK>
__global__ __launch_bounds__(256, 2) void gemm96_k(
    const float* __restrict__ In, const float* __restrict__ W,
    const float* __restrict__ bias, float* __restrict__ Out,
    float* __restrict__ Out2, const float* __restrict__ zg,
    const float* __restrict__ lnG, const float* __restrict__ lnB,
    const float* __restrict__ scal_c, const float* __restrict__ scal_a,
    int N, size_t inStride, size_t outStride) {
  __shared__ float Wt[9216];                       // [k][co]
  __shared__ float buf[BK * 256];                  // In tile
  __shared__ float zbuf[(EPI == 2) ? BK * 256 : 4];
  int tid = threadIdx.x;
  int wv = tid >> 6, ln = tid & 63;
  for (int i = tid; i < 9216; i += 256) {
    int co = i / 96, k = i - co * 96;
    Wt[k * 96 + co] = W[i];
  }
  int out_g = tid >> 6;
  int tok_g = tid & 63;
  int n0 = blockIdx.x * 256 + tok_g * 4;
  int co0 = out_g * 24;
  const float* ipb = In + blockIdx.y * inStride + blockIdx.x * 256 + ln * 4;
  const float* zpb = (EPI == 2) ? (zg + blockIdx.y * inStride + blockIdx.x * 256 + ln * 4)
                                : nullptr;
  const float* ip = In + blockIdx.y * inStride + n0;

  float4 mu4, rs4;
  if (EPI == 2) {   // per-token LN stats (bulk independent loads, latency-tolerant)
    float4 sum = make_float4(0.f, 0.f, 0.f, 0.f);
    float4 sq  = make_float4(0.f, 0.f, 0.f, 0.f);
#pragma unroll 8
    for (int ci = 0; ci < 96; ++ci) {
      float4 t = *(const float4*)(ip + (size_t)ci * N);
      sum.x += t.x; sum.y += t.y; sum.z += t.z; sum.w += t.w;
      sq.x = fmaf(t.x, t.x, sq.x); sq.y = fmaf(t.y, t.y, sq.y);
      sq.z = fmaf(t.z, t.z, sq.z); sq.w = fmaf(t.w, t.w, sq.w);
    }
    const float r96 = 1.0f / 96.0f;
    mu4.x = sum.x * r96; mu4.y = sum.y * r96; mu4.z = sum.z * r96; mu4.w = sum.w * r96;
    rs4.x = rsqrtf(fmaxf(sq.x * r96 - mu4.x * mu4.x, 0.f) + 1e-5f);
    rs4.y = rsqrtf(fmaxf(sq.y * r96 - mu4.y * mu4.y, 0.f) + 1e-5f);
    rs4.z = rsqrtf(fmaxf(sq.z * r96 - mu4.z * mu4.z, 0.f) + 1e-5f);
    rs4.w = rsqrtf(fmaxf(sq.w * r96 - mu4.w * mu4.w, 0.f) + 1e-5f);
  }

  float4 acc[24];
#pragma unroll
  for (int j = 0; j < 24; ++j) {
    float bj = bias[co0 + j];
    acc[j] = make_float4(bj, bj, bj, bj);
  }

  constexpr int NT  = 96 / BK;
  constexpr int RPW = BK / 4;   // rows staged per wave
  float4 pin[RPW];
  float4 pz[(EPI == 2) ? RPW : 1];
#pragma unroll
  for (int i = 0; i < RPW; ++i) {
    pin[i] = *(const float4*)(ipb + (size_t)(i * 4 + wv) * N);
    if (EPI == 2) pz[i] = *(const float4*)(zpb + (size_t)(i * 4 + wv) * N);
  }
#pragma unroll 1
  for (int kb = 0; kb < NT; ++kb) {
#pragma unroll
    for (int i = 0; i < RPW; ++i) {
      *(float4*)&buf[(i * 4 + wv) * 256 + ln * 4] = pin[i];
      if (EPI == 2) *(float4*)&zbuf[(i * 4 + wv) * 256 + ln * 4] = pz[i];
    }
    __syncthreads();
    if (kb + 1 < NT) {   // prefetch next tile into regs; overlaps compute below
#pragma unroll
      for (int i = 0; i < RPW; ++i) {
        pin[i] = *(const float4*)(ipb + (size_t)((kb + 1) * BK + i * 4 + wv) * N);
        if (EPI == 2) pz[i] = *(const float4*)(zpb + (size_t)((kb + 1) * BK + i * 4 + wv) * N);
      }
    }
#pragma unroll
    for (int kk = 0; kk < BK; ++kk) {
      int k = kb * BK + kk;
      float4 v = *(const float4*)&buf[kk * 256 + tok_g * 4];
      if (EPI == 2) {
        float4 zz = *(const float4*)&zbuf[kk * 256 + tok_g * 4];
        float lgk = lnG[k], lbk = lnB[k];
        float gx = zz.x * __builtin_amdgcn_rcpf(1.0f + __expf(-zz.x));
        float gy = zz.y * __builtin_amdgcn_rcpf(1.0f + __expf(-zz.y));
        float gz = zz.z * __builtin_amdgcn_rcpf(1.0f + __expf(-zz.z));
        float gw = zz.w * __builtin_amdgcn_rcpf(1.0f + __expf(-zz.w));
        v.x = fmaf((v.x - mu4.x) * rs4.x, lgk, lbk) * gx;
        v.y = fmaf((v.y - mu4.y) * rs4.y, lgk, lbk) * gy;
        v.z = fmaf((v.z - mu4.z) * rs4.z, lgk, lbk) * gz;
        v.w = fmaf((v.w - mu4.w) * rs4.w, lgk, lbk) * gw;
      }
      const float4* wr = (const float4*)&Wt[k * 96 + co0];
#pragma unroll
      for (int j = 0; j < 6; ++j) {
        float4 wvv = wr[j];
        FMA4(acc[4 * j + 0], wvv.x);
        FMA4(acc[4 * j + 1], wvv.y);
        FMA4(acc[4 * j + 2], wvv.z);
        FMA4(acc[4 * j + 3], wvv.w);
      }
    }
    __syncthreads();
  }

  if (EPI == 1) {
    float cv = scal_c[0], al = scal_a[0];
    float rc = 1.0f / (cv + 1e-8f);
#pragma unroll 4
    for (int j = 0; j < 24; ++j) {
      float4 a4, b4;
      float t, tau, ct, damp, sc, cc;
      t = acc[j].x; tau = 0.5f * t * (1.0f + erff(t * 0.70710678118654752f));
      ct = cv * tau; damp = expf(-0.5f * al * tau); sincosf(ct, &sc, &cc);
      a4.x = damp * (cc + sc * al * 0.5f * rc); b4.x = damp * sc * rc;
      t = acc[j].y; tau = 0.5f * t * (1.0f + erff(t * 0.70710678118654752f));
      ct = cv * tau; damp = expf(-0.5f * al * tau); sincosf(ct, &sc, &cc);
      a4.y = damp * (cc + sc * al * 0.5f * rc); b4.y = damp * sc * rc;
      t = acc[j].z; tau = 0.5f * t * (1.0f + erff(t * 0.70710678118654752f));
      ct = cv * tau; damp = expf(-0.5f * al * tau); sincosf(ct, &sc, &cc);
      a4.z = damp * (cc + sc * al * 0.5f * rc); b4.z = damp * sc * rc;
      t = acc[j].w; tau = 0.5f * t * (1.0f + erff(t * 0.70710678118654752f));
      ct = cv * tau; damp = expf(-0.5f * al * tau); sincosf(ct, &sc, &cc);
      a4.w = damp * (cc + sc * al * 0.5f * rc); b4.w = damp * sc * rc;
      *(float4*)(Out  + (size_t)(co0 + j) * N + n0) = a4;
      *(float4*)(Out2 + (size_t)(co0 + j) * N + n0) = b4;
    }
  } else {
    float* op = Out + blockIdx.y * outStride + n0;
#pragma unroll
    for (int j = 0; j < 24; ++j)
      *(float4*)(op + (size_t)(co0 + j) * N) = acc[j];
  }
}

// ---------------- fused W+H (I)DCT on one 64x64 plane ------------------------
template <bool DCT>
__global__ __launch_bounds__(256) void wh_k(const float* __restrict__ in,
    float* __restrict__ out, const float* __restrict__ b64) {
  __shared__ float XT[64 * 68];
  __shared__ float Yb[64 * 68];
  __shared__ float Bs[64 * 68];
  int tid = threadIdx.x;
  const float* ip = in + (size_t)blockIdx.x * HW;
  float* op = out + (size_t)blockIdx.x * HW;
  for (int i = tid; i < 4096; i += 256) {
    int r = i >> 6, cdx = i & 63;
    Bs[r * 68 + cdx] = DCT ? b64[cdx * 64 + r] : b64[r * 64 + cdx];
  }
  for (int i = tid; i < 4096; i += 256) {
    int h = i >> 6, w = i & 63;
    XT[w * 68 + h] = ip[i];
  }
  __syncthreads();
  int n = tid & 63;
  int g = tid >> 6;
  {
    float acc[16];
#pragma unroll
    for (int i = 0; i < 16; ++i) acc[i] = 0.0f;
#pragma unroll 4
    for (int w = 0; w < 64; ++w) {
      float bv = Bs[w * 68 + n];
      const float4* xw = (const float4*)&XT[w * 68 + g * 16];
      float4 x0 = xw[0], x1 = xw[1], x2 = xw[2], x3 = xw[3];
      acc[0]  += x0.x * bv; acc[1]  += x0.y * bv; acc[2]  += x0.z * bv; acc[3]  += x0.w * bv;
      acc[4]  += x1.x * bv; acc[5]  += x1.y * bv; acc[6]  += x1.z * bv; acc[7]  += x1.w * bv;
      acc[8]  += x2.x * bv; acc[9]  += x2.y * bv; acc[10] += x2.z * bv; acc[11] += x2.w * bv;
      acc[12] += x3.x * bv; acc[13] += x3.y * bv; acc[14] += x3.z * bv; acc[15] += x3.w * bv;
    }
#pragma unroll
    for (int i = 0; i < 16; ++i) Yb[(g * 16 + i) * 68 + n] = acc[i];
  }
  __syncthreads();
  {
    float acc[16];
#pragma unroll
    for (int i = 0; i < 16; ++i) acc[i] = 0.0f;
#pragma unroll 4
    for (int h = 0; h < 64; ++h) {
      float yv = Yb[h * 68 + n];
      const float4* bw = (const float4*)&Bs[h * 68 + g * 16];
      float4 b0 = bw[0], b1 = bw[1], b2 = bw[2], b3 = bw[3];
      acc[0]  += b0.x * yv; acc[1]  += b0.y * yv; acc[2]  += b0.z * yv; acc[3]  += b0.w * yv;
      acc[4]  += b1.x * yv; acc[5]  += b1.y * yv; acc[6]  += b1.z * yv; acc[7]  += b1.w * yv;
      acc[8]  += b2.x * yv; acc[9]  += b2.y * yv; acc[10] += b2.z * yv; acc[11] += b2.w * yv;
      acc[12] += b3.x * yv; acc[13] += b3.y * yv; acc[14] += b3.z * yv; acc[15] += b3.w * yv;
    }
#pragma unroll
    for (int i = 0; i < 16; ++i) op[(g * 16 + i) * 64 + n] = acc[i];
  }
}

// ---------------- fused T-DCT + spectral multiply + T-IDCT -------------------
__global__ __launch_bounds__(256) void tspec_k(const float* __restrict__ U0,
    const float* __restrict__ V0, const float* __restrict__ A,
    const float* __restrict__ Bc, const float* __restrict__ b16,
    float* __restrict__ out) {
  __shared__ float bs[256];
  int tid = threadIdx.x;
  bs[tid] = b16[tid];
  __syncthreads();
  int hw = blockIdx.x * 256 + tid;
  int c = blockIdx.y, b = blockIdx.z;
  size_t base = ((size_t)(b * C96 + c) * 16) * HW + hw;
  int cbase = c * THW + hw;
  float u[16], v[16];
#pragma unroll
  for (int t = 0; t < 16; ++t) { u[t] = U0[base + t * HW]; v[t] = V0[base + t * HW]; }
  float so[16];
#pragma unroll
  for (int n = 0; n < 16; ++n) {
    float ua = 0.0f, va = 0.0f;
#pragma unroll
    for (int t = 0; t < 16; ++t) { float bb = bs[n * 16 + t]; ua += bb * u[t]; va += bb * v[t]; }
    so[n] = A[cbase + n * HW] * ua + Bc[cbase + n * HW] * va;
  }
#pragma unroll
  for (int t = 0; t < 16; ++t) {
    float acc = 0.0f;
#pragma unroll
    for (int n = 0; n < 16; ++n) acc += so[n] * bs[n * 16 + t];
    out[base + t * HW] = acc;
  }
}

extern "C" void kernel_launch(void* const* d_in, const int* in_sizes, int n_in,
                              void* d_out, int out_size, void* d_ws, size_t ws_size,
                              hipStream_t stream) {
  const float* x    = (const float*)d_in[0];
  const float* fe   = (const float*)d_in[1];
  const float* dww  = (const float*)d_in[2];
  const float* dwb  = (const float*)d_in[3];
  const float* linW = (const float*)d_in[4];
  const float* linB = (const float*)d_in[5];
  const float* v0W  = (const float*)d_in[6];
  const float* v0B  = (const float*)d_in[7];
  const float* tokW = (const float*)d_in[8];
  const float* tokB = (const float*)d_in[9];
  const float* cS   = (const float*)d_in[10];
  const float* aS   = (const float*)d_in[11];
  const float* lnG  = (const float*)d_in[12];
  const float* lnBp = (const float*)d_in[13];
  const float* outW = (const float*)d_in[14];
  const float* outB = (const float*)d_in[15];
  float* out = (float*)d_out;

  float* w = (float*)d_ws;
  const size_t TEN = (size_t)2 * C96 * THW;
  const size_t BST = (size_t)C96 * THW;
  float* b64    = w;
  float* b16    = w + 4096;
  float* buf_y  = w + 8192;
  float* buf_xg = buf_y + TEN;
  float* buf_z  = buf_xg + TEN;
  float* buf_v0 = buf_z + TEN;
  float* bufA   = buf_v0 + TEN;
  float* bufB   = bufA + BST;
  size_t need = (size_t)(8192 + 4 * TEN + 2 * BST) * sizeof(float);
  if (ws_size < need) return;

  hipLaunchKernelGGL(init_basis_k, dim3(1), dim3(256), 0, stream, b64, b16);
  hipLaunchKernelGGL(dwconv_k, dim3(8, 192), dim3(256), 0, stream, x, dww, dwb, buf_y);
  hipLaunchKernelGGL((gemm96_k<0, 16>), dim3(256, 2), dim3(256), 0, stream,
                     buf_y, linW, linB, buf_xg, (float*)nullptr, (const float*)nullptr,
                     (const float*)nullptr, (const float*)nullptr,
                     (const float*)nullptr, (const float*)nullptr, THW, BST, BST);
  hipLaunchKernelGGL((gemm96_k<0, 16>), dim3(256, 2), dim3(256), 0, stream,
                     buf_y, linW + 9216, linB + 96, buf_z, (float*)nullptr, (const float*)nullptr,
                     (const float*)nullptr, (const float*)nullptr,
                     (const float*)nullptr, (const float*)nullptr, THW, BST, BST);
  hipLaunchKernelGGL(feT_k, dim3(1024), dim3(256), 0, stream, fe, buf_v0);
  hipLaunchKernelGGL((gemm96_k<1, 16>), dim3(256, 1), dim3(256), 0, stream,
                     buf_v0, tokW, tokB, bufA, bufB, (const float*)nullptr,
                     (const float*)nullptr, (const float*)nullptr,
                     cS, aS, THW, (size_t)0, (size_t)0);
  hipLaunchKernelGGL((gemm96_k<0, 16>), dim3(256, 2), dim3(256), 0, stream,
                     buf_xg, v0W, v0B, buf_v0, (float*)nullptr, (const float*)nullptr,
                     (const float*)nullptr, (const float*)nullptr,
                     (const float*)nullptr, (const float*)nullptr, THW, BST, BST);
  hipLaunchKernelGGL(wh_k<true>, dim3(3072), dim3(256), 0, stream, buf_xg, buf_y, b64);
  hipLaunchKernelGGL(wh_k<true>, dim3(3072), dim3(256), 0, stream, buf_v0, buf_xg, b64);
  hipLaunchKernelGGL(tspec_k, dim3(16, 96, 2), dim3(256), 0, stream, buf_y, buf_xg, bufA, bufB, b16, buf_v0);
  hipLaunchKernelGGL(wh_k<false>, dim3(3072), dim3(256), 0, stream, buf_v0, buf_y, b64);
  hipLaunchKernelGGL((gemm96_k<2, 8>), dim3(256, 2), dim3(256), 0, stream,
                     buf_y, outW, outB, out, (float*)nullptr, buf_z,
                     lnG, lnBp, (const float*)nullptr, (const float*)nullptr, THW, BST, BST);
}

// Round 4
// 979.879 us; speedup vs baseline: 1.0145x; 1.0145x over previous
//
#include <hip/hip_runtime.h>
#include <math.h>

#define THW 65536
#define HW  4096
#define C96 96
#ifndef M_PI
#define M_PI 3.14159265358979323846
#endif

// ---------------- basis init (once per launch; ws is re-poisoned each call) --
__global__ __launch_bounds__(256) void init_basis_k(float* __restrict__ b64,
                                                    float* __restrict__ b16) {
  int tid = threadIdx.x;
  for (int i = tid; i < 4096; i += 256) {
    int n = i >> 6, x = i & 63;
    double s = sqrt(2.0 / 64.0) * (n == 0 ? sqrt(0.5) : 1.0);
    b64[i] = (float)(cos((double)n * ((double)x + 0.5) * M_PI / 64.0) * s);
  }
  {
    int n = tid >> 4, x = tid & 15;
    double s = sqrt(2.0 / 16.0) * (n == 0 ? sqrt(0.5) : 1.0);
    b16[tid & 255] = (float)(cos((double)n * ((double)x + 0.5) * M_PI / 16.0) * s);
  }
}

// ---------------- depthwise 3x3x3 conv: LDS planes + sliding h-window --------
__global__ __launch_bounds__(256, 2) void dwconv_k(const float* __restrict__ x,
    const float* __restrict__ wv, const float* __restrict__ bias,
    float* __restrict__ y) {
  __shared__ float lds[4 * 66 * 72];  // 76 KB
  int tid = threadIdx.x;
  int t0 = blockIdx.x * 2;
  int bc = blockIdx.y;
  int c  = bc % C96;
  const float* xp = x + (size_t)bc * THW;

  float4 z4 = make_float4(0.f, 0.f, 0.f, 0.f);
  for (int i = tid; i < 4752; i += 256) ((float4*)lds)[i] = z4;
  __syncthreads();
  for (int p = 0; p < 4; ++p) {
    int tt = t0 - 1 + p;
    if (tt < 0 || tt > 15) continue;
    const float* pp = xp + tt * HW;
    for (int i = tid; i < 1024; i += 256) {
      int row = i >> 4, c4 = i & 15;
      float4 v = *(const float4*)(pp + row * 64 + c4 * 4);
      *(float4*)&lds[(p * 66 + row + 1) * 72 + 4 + c4 * 4] = v;
    }
  }
  float w27[27];
#pragma unroll
  for (int i = 0; i < 27; ++i) w27[i] = wv[c * 27 + i];
  float bv = bias[c];
  __syncthreads();

  int s   = tid & 7;
  int tc  = (tid >> 3) & 1;
  int seg = tid >> 4;
  int h0 = seg * 4;
  int cb = 3 + 8 * s;

  float win[3][3][10];
#define LOADROW(q, slot, ldsrow) { \
    const float* rp = &lds[(((tc) + (q)) * 66 + (ldsrow)) * 72 + cb]; \
    _Pragma("unroll") for (int j = 0; j < 10; ++j) win[q][slot][j] = rp[j]; }

#pragma unroll
  for (int q = 0; q < 3; ++q) { LOADROW(q, 0, h0); LOADROW(q, 1, h0 + 1); }

  float* yp = y + (size_t)bc * THW + (t0 + tc) * HW + s * 8;
#pragma unroll
  for (int st = 0; st < 4; ++st) {
    int h = h0 + st;
#pragma unroll
    for (int q = 0; q < 3; ++q) { LOADROW(q, (st + 2) % 3, h + 2); }
    float acc[8];
#pragma unroll
    for (int w = 0; w < 8; ++w) acc[w] = bv;
#pragma unroll
    for (int q = 0; q < 3; ++q)
#pragma unroll
      for (int rr = 0; rr < 3; ++rr) {
        const float* row = win[q][(st + rr) % 3];
#pragma unroll
        for (int dw = 0; dw < 3; ++dw) {
          float coef = w27[q * 9 + rr * 3 + dw];
#pragma unroll
          for (int w = 0; w < 8; ++w) acc[w] = fmaf(row[w + dw], coef, acc[w]);
        }
      }
    *(float4*)&yp[h * 64]     = make_float4(acc[0], acc[1], acc[2], acc[3]);
    *(float4*)&yp[h * 64 + 4] = make_float4(acc[4], acc[5], acc[6], acc[7]);
  }
#undef LOADROW
}

// ---------------- fe transpose: [THW][96] -> [96][THW] -----------------------
__global__ __launch_bounds__(256) void feT_k(const float* __restrict__ fe,
                                             float* __restrict__ feT) {
  __shared__ float t[96 * 65];
  int tid = threadIdx.x;
  int tok0 = blockIdx.x * 64;
  const float* p = fe + (size_t)tok0 * 96;
  for (int i = tid; i < 6144; i += 256) {
    int tok = i / 96;
    int ch = i - tok * 96;
    t[ch * 65 + tok] = p[i];
  }
  __syncthreads();
  for (int i = tid; i < 6144; i += 256) {
    int ch = i >> 6, tok = i & 63;
    feT[(size_t)ch * THW + tok0 + tok] = t[ch * 65 + tok];
  }
}

// ---------------- LDS-staged 96xN GEMM family (low register pressure) --------
// Out[co][n] = sum_k W[co][k] * In[k][n]  (+ epilogue)
// EPI 0: + bias, plain store
// EPI 1: tau: t=acc; tau=gelu(t); write A,B spectral maps
// EPI 2: LN+SiLU-gate applied to In at STAGING time (k-loop is pure GEMM)
#define FMA4(A, WV) \
  A.x = fmaf(WV, v.x, A.x); A.y = fmaf(WV, v.y, A.y); \
  A.z = fmaf(WV, v.z, A.z); A.w = fmaf(WV, v.w, A.w);

#define WPAD 104
#define BK32 32

template <int EPI>
__global__ __launch_bounds__(256, 2) void gemm96_k(
    const float* __restrict__ In, const float* __restrict__ W,
    const float* __restrict__ bias, float* __restrict__ Out,
    float* __restrict__ Out2, const float* __restrict__ zg,
    const float* __restrict__ lnG, const float* __restrict__ lnB,
    const float* __restrict__ scal_c, const float* __restrict__ scal_a,
    int N, size_t inStride, size_t outStride) {
  __shared__ float Wt[96 * WPAD];      // [k][co], padded row (39 KB)
  __shared__ float buf[BK32 * 256];    // 32 KB
  int tid = threadIdx.x;
  int wvi = tid >> 6, ln = tid & 63;
  // conflict-free transposed fill: consecutive lanes -> consecutive co
  for (int i = tid; i < 2304; i += 256) {
    int k4 = i / 96, co = i - k4 * 96;
    float4 w4 = *(const float4*)(W + co * 96 + k4 * 4);
    int k = k4 * 4;
    Wt[(k + 0) * WPAD + co] = w4.x;
    Wt[(k + 1) * WPAD + co] = w4.y;
    Wt[(k + 2) * WPAD + co] = w4.z;
    Wt[(k + 3) * WPAD + co] = w4.w;
  }
  int tok_g = ln;
  int n0 = blockIdx.x * 256 + tok_g * 4;
  int co0 = wvi * 24;
  const float* ipb = In + blockIdx.y * inStride + blockIdx.x * 256 + ln * 4;
  const float* zpb = (EPI == 2) ? (zg + blockIdx.y * inStride + blockIdx.x * 256 + ln * 4)
                                : nullptr;

  float4 mu4, rs4;
  if (EPI == 2) {   // per-token LN stats for this lane's 4 tokens
    float4 sum = make_float4(0.f, 0.f, 0.f, 0.f);
    float4 sq  = make_float4(0.f, 0.f, 0.f, 0.f);
#pragma unroll 8
    for (int ci = 0; ci < 96; ++ci) {
      float4 t = *(const float4*)(ipb + (size_t)ci * N);
      sum.x += t.x; sum.y += t.y; sum.z += t.z; sum.w += t.w;
      sq.x = fmaf(t.x, t.x, sq.x); sq.y = fmaf(t.y, t.y, sq.y);
      sq.z = fmaf(t.z, t.z, sq.z); sq.w = fmaf(t.w, t.w, sq.w);
    }
    const float r96 = 1.0f / 96.0f;
    mu4.x = sum.x * r96; mu4.y = sum.y * r96; mu4.z = sum.z * r96; mu4.w = sum.w * r96;
    rs4.x = rsqrtf(fmaxf(sq.x * r96 - mu4.x * mu4.x, 0.f) + 1e-5f);
    rs4.y = rsqrtf(fmaxf(sq.y * r96 - mu4.y * mu4.y, 0.f) + 1e-5f);
    rs4.z = rsqrtf(fmaxf(sq.z * r96 - mu4.z * mu4.z, 0.f) + 1e-5f);
    rs4.w = rsqrtf(fmaxf(sq.w * r96 - mu4.w * mu4.w, 0.f) + 1e-5f);
  }

  float4 acc[24];
#pragma unroll
  for (int j = 0; j < 24; ++j) {
    float bj = bias[co0 + j];
    acc[j] = make_float4(bj, bj, bj, bj);
  }

  constexpr int NT  = 96 / BK32;
  constexpr int RPW = BK32 / 4;   // 8 rows staged per wave per tile
#pragma unroll 1
  for (int kb = 0; kb < NT; ++kb) {
    // stage tile kb (transient registers only)
#pragma unroll
    for (int i = 0; i < RPW; ++i) {
      int r = i * 4 + wvi;
      int k = kb * BK32 + r;
      float4 v4 = *(const float4*)(ipb + (size_t)k * N);
      if (EPI == 2) {
        float4 zz = *(const float4*)(zpb + (size_t)k * N);
        float lgk = lnG[k], lbk = lnB[k];
        float gx = zz.x * __builtin_amdgcn_rcpf(1.0f + __expf(-zz.x));
        float gy = zz.y * __builtin_amdgcn_rcpf(1.0f + __expf(-zz.y));
        float gz = zz.z * __builtin_amdgcn_rcpf(1.0f + __expf(-zz.z));
        float gw = zz.w * __builtin_amdgcn_rcpf(1.0f + __expf(-zz.w));
        v4.x = fmaf((v4.x - mu4.x) * rs4.x, lgk, lbk) * gx;
        v4.y = fmaf((v4.y - mu4.y) * rs4.y, lgk, lbk) * gy;
        v4.z = fmaf((v4.z - mu4.z) * rs4.z, lgk, lbk) * gz;
        v4.w = fmaf((v4.w - mu4.w) * rs4.w, lgk, lbk) * gw;
      }
      *(float4*)&buf[r * 256 + ln * 4] = v4;
    }
    __syncthreads();
#pragma unroll
    for (int kk = 0; kk < BK32; ++kk) {
      int k = kb * BK32 + kk;
      float4 v = *(const float4*)&buf[kk * 256 + tok_g * 4];
      const float4* wr = (const float4*)&Wt[k * WPAD + co0];
#pragma unroll
      for (int j = 0; j < 6; ++j) {
        float4 wvv = wr[j];
        FMA4(acc[4 * j + 0], wvv.x);
        FMA4(acc[4 * j + 1], wvv.y);
        FMA4(acc[4 * j + 2], wvv.z);
        FMA4(acc[4 * j + 3], wvv.w);
      }
    }
    __syncthreads();
  }

  if (EPI == 1) {
    float cv = scal_c[0], al = scal_a[0];
    float rc = 1.0f / (cv + 1e-8f);
#define TAUMAP(T, AA, BB) { \
    float tau = 0.5f * (T) * (1.0f + erff((T) * 0.70710678118654752f)); \
    float ct = cv * tau; \
    float damp = __expf(-0.5f * al * tau); \
    float sc = __sinf(ct), cc = __cosf(ct); \
    AA = damp * (cc + sc * al * 0.5f * rc); BB = damp * sc * rc; }
#pragma unroll 2
    for (int j = 0; j < 24; ++j) {
      float4 a4, b4;
      TAUMAP(acc[j].x, a4.x, b4.x);
      TAUMAP(acc[j].y, a4.y, b4.y);
      TAUMAP(acc[j].z, a4.z, b4.z);
      TAUMAP(acc[j].w, a4.w, b4.w);
      *(float4*)(Out  + (size_t)(co0 + j) * N + n0) = a4;
      *(float4*)(Out2 + (size_t)(co0 + j) * N + n0) = b4;
    }
#undef TAUMAP
  } else {
    float* op = Out + blockIdx.y * outStride + n0;
#pragma unroll
    for (int j = 0; j < 24; ++j)
      *(float4*)(op + (size_t)(co0 + j) * N) = acc[j];
  }
}

// ---------------- fused W+H (I)DCT on one 64x64 plane ------------------------
template <bool DCT>
__global__ __launch_bounds__(256) void wh_k(const float* __restrict__ in,
    float* __restrict__ out, const float* __restrict__ b64) {
  __shared__ float XT[64 * 68];
  __shared__ float Yb[64 * 68];
  __shared__ float Bs[64 * 68];
  int tid = threadIdx.x;
  const float* ip = in + (size_t)blockIdx.x * HW;
  float* op = out + (size_t)blockIdx.x * HW;
  for (int i = tid; i < 4096; i += 256) {
    int r = i >> 6, cdx = i & 63;
    Bs[r * 68 + cdx] = DCT ? b64[cdx * 64 + r] : b64[r * 64 + cdx];
  }
  for (int i = tid; i < 4096; i += 256) {
    int h = i >> 6, w = i & 63;
    XT[w * 68 + h] = ip[i];
  }
  __syncthreads();
  int n = tid & 63;
  int g = tid >> 6;
  {
    float acc[16];
#pragma unroll
    for (int i = 0; i < 16; ++i) acc[i] = 0.0f;
#pragma unroll 4
    for (int w = 0; w < 64; ++w) {
      float bv = Bs[w * 68 + n];
      const float4* xw = (const float4*)&XT[w * 68 + g * 16];
      float4 x0 = xw[0], x1 = xw[1], x2 = xw[2], x3 = xw[3];
      acc[0]  += x0.x * bv; acc[1]  += x0.y * bv; acc[2]  += x0.z * bv; acc[3]  += x0.w * bv;
      acc[4]  += x1.x * bv; acc[5]  += x1.y * bv; acc[6]  += x1.z * bv; acc[7]  += x1.w * bv;
      acc[8]  += x2.x * bv; acc[9]  += x2.y * bv; acc[10] += x2.z * bv; acc[11] += x2.w * bv;
      acc[12] += x3.x * bv; acc[13] += x3.y * bv; acc[14] += x3.z * bv; acc[15] += x3.w * bv;
    }
#pragma unroll
    for (int i = 0; i < 16; ++i) Yb[(g * 16 + i) * 68 + n] = acc[i];
  }
  __syncthreads();
  {
    float acc[16];
#pragma unroll
    for (int i = 0; i < 16; ++i) acc[i] = 0.0f;
#pragma unroll 4
    for (int h = 0; h < 64; ++h) {
      float yv = Yb[h * 68 + n];
      const float4* bw = (const float4*)&Bs[h * 68 + g * 16];
      float4 b0 = bw[0], b1 = bw[1], b2 = bw[2], b3 = bw[3];
      acc[0]  += b0.x * yv; acc[1]  += b0.y * yv; acc[2]  += b0.z * yv; acc[3]  += b0.w * yv;
      acc[4]  += b1.x * yv; acc[5]  += b1.y * yv; acc[6]  += b1.z * yv; acc[7]  += b1.w * yv;
      acc[8]  += b2.x * yv; acc[9]  += b2.y * yv; acc[10] += b2.z * yv; acc[11] += b2.w * yv;
      acc[12] += b3.x * yv; acc[13] += b3.y * yv; acc[14] += b3.z * yv; acc[15] += b3.w * yv;
    }
#pragma unroll
    for (int i = 0; i < 16; ++i) op[(g * 16 + i) * 64 + n] = acc[i];
  }
}

// ---------------- fused T-DCT + spectral multiply + T-IDCT -------------------
__global__ __launch_bounds__(256) void tspec_k(const float* __restrict__ U0,
    const float* __restrict__ V0, const float* __restrict__ A,
    const float* __restrict__ Bc, const float* __restrict__ b16,
    float* __restrict__ out) {
  __shared__ float bs[256];
  int tid = threadIdx.x;
  bs[tid] = b16[tid];
  __syncthreads();
  int hw = blockIdx.x * 256 + tid;
  int c = blockIdx.y, b = blockIdx.z;
  size_t base = ((size_t)(b * C96 + c) * 16) * HW + hw;
  int cbase = c * THW + hw;
  float u[16], v[16];
#pragma unroll
  for (int t = 0; t < 16; ++t) { u[t] = U0[base + t * HW]; v[t] = V0[base + t * HW]; }
  float so[16];
#pragma unroll
  for (int n = 0; n < 16; ++n) {
    float ua = 0.0f, va = 0.0f;
#pragma unroll
    for (int t = 0; t < 16; ++t) { float bb = bs[n * 16 + t]; ua += bb * u[t]; va += bb * v[t]; }
    so[n] = A[cbase + n * HW] * ua + Bc[cbase + n * HW] * va;
  }
#pragma unroll
  for (int t = 0; t < 16; ++t) {
    float acc = 0.0f;
#pragma unroll
    for (int n = 0; n < 16; ++n) acc += so[n] * bs[n * 16 + t];
    out[base + t * HW] = acc;
  }
}

extern "C" void kernel_launch(void* const* d_in, const int* in_sizes, int n_in,
                              void* d_out, int out_size, void* d_ws, size_t ws_size,
                              hipStream_t stream) {
  const float* x    = (const float*)d_in[0];
  const float* fe   = (const float*)d_in[1];
  const float* dww  = (const float*)d_in[2];
  const float* dwb  = (const float*)d_in[3];
  const float* linW = (const float*)d_in[4];
  const float* linB = (const float*)d_in[5];
  const float* v0W  = (const float*)d_in[6];
  const float* v0B  = (const float*)d_in[7];
  const float* tokW = (const float*)d_in[8];
  const float* tokB = (const float*)d_in[9];
  const float* cS   = (const float*)d_in[10];
  const float* aS   = (const float*)d_in[11];
  const float* lnG  = (const float*)d_in[12];
  const float* lnBp = (const float*)d_in[13];
  const float* outW = (const float*)d_in[14];
  const float* outB = (const float*)d_in[15];
  float* out = (float*)d_out;

  float* w = (float*)d_ws;
  const size_t TEN = (size_t)2 * C96 * THW;
  const size_t BST = (size_t)C96 * THW;
  float* b64    = w;
  float* b16    = w + 4096;
  float* buf_y  = w + 8192;
  float* buf_xg = buf_y + TEN;
  float* buf_z  = buf_xg + TEN;
  float* buf_v0 = buf_z + TEN;
  float* bufA   = buf_v0 + TEN;
  float* bufB   = bufA + BST;
  size_t need = (size_t)(8192 + 4 * TEN + 2 * BST) * sizeof(float);
  if (ws_size < need) return;

  hipLaunchKernelGGL(init_basis_k, dim3(1), dim3(256), 0, stream, b64, b16);
  hipLaunchKernelGGL(dwconv_k, dim3(8, 192), dim3(256), 0, stream, x, dww, dwb, buf_y);
  hipLaunchKernelGGL((gemm96_k<0>), dim3(256, 2), dim3(256), 0, stream,
                     buf_y, linW, linB, buf_xg, (float*)nullptr, (const float*)nullptr,
                     (const float*)nullptr, (const float*)nullptr,
                     (const float*)nullptr, (const float*)nullptr, THW, BST, BST);
  hipLaunchKernelGGL((gemm96_k<0>), dim3(256, 2), dim3(256), 0, stream,
                     buf_y, linW + 9216, linB + 96, buf_z, (float*)nullptr, (const float*)nullptr,
                     (const float*)nullptr, (const float*)nullptr,
                     (const float*)nullptr, (const float*)nullptr, THW, BST, BST);
  hipLaunchKernelGGL(feT_k, dim3(1024), dim3(256), 0, stream, fe, buf_v0);
  hipLaunchKernelGGL((gemm96_k<1>), dim3(256, 1), dim3(256), 0, stream,
                     buf_v0, tokW, tokB, bufA, bufB, (const float*)nullptr,
                     (const float*)nullptr, (const float*)nullptr,
                     cS, aS, THW, (size_t)0, (size_t)0);
  hipLaunchKernelGGL((gemm96_k<0>), dim3(256, 2), dim3(256), 0, stream,
                     buf_xg, v0W, v0B, buf_v0, (float*)nullptr, (const float*)nullptr,
                     (const float*)nullptr, (const float*)nullptr,
                     (const float*)nullptr, (const float*)nullptr, THW, BST, BST);
  hipLaunchKernelGGL(wh_k<true>, dim3(3072), dim3(256), 0, stream, buf_xg, buf_y, b64);
  hipLaunchKernelGGL(wh_k<true>, dim3(3072), dim3(256), 0, stream, buf_v0, buf_xg, b64);
  hipLaunchKernelGGL(tspec_k, dim3(16, 96, 2), dim3(256), 0, stream, buf_y, buf_xg, bufA, bufB, b16, buf_v0);
  hipLaunchKernelGGL(wh_k<false>, dim3(3072), dim3(256), 0, stream, buf_v0, buf_y, b64);
  hipLaunchKernelGGL((gemm96_k<2>), dim3(256, 2), dim3(256), 0, stream,
                     buf_y, outW, outB, out, (float*)nullptr, buf_z,
                     lnG, lnBp, (const float*)nullptr, (const float*)nullptr, THW, BST, BST);
}

// Round 5
// 712.459 us; speedup vs baseline: 1.3953x; 1.3753x over previous
//
#include <hip/hip_runtime.h>
#include <math.h>

#define THW 65536
#define HW  4096
#define C96 96
#ifndef M_PI
#define M_PI 3.14159265358979323846
#endif

// ---------------- basis init (once per launch; ws is re-poisoned each call) --
__global__ __launch_bounds__(256) void init_basis_k(float* __restrict__ b64,
                                                    float* __restrict__ b16) {
  int tid = threadIdx.x;
  for (int i = tid; i < 4096; i += 256) {
    int n = i >> 6, x = i & 63;
    double s = sqrt(2.0 / 64.0) * (n == 0 ? sqrt(0.5) : 1.0);
    b64[i] = (float)(cos((double)n * ((double)x + 0.5) * M_PI / 64.0) * s);
  }
  {
    int n = tid >> 4, x = tid & 15;
    double s = sqrt(2.0 / 16.0) * (n == 0 ? sqrt(0.5) : 1.0);
    b16[tid & 255] = (float)(cos((double)n * ((double)x + 0.5) * M_PI / 16.0) * s);
  }
}

// ---------------- depthwise 3x3x3 conv: LDS planes + sliding h-window --------
// NOTE: no min-waves arg in __launch_bounds__ — the (N,2) form empirically
// caps the VGPR grant at ~100 on this compiler and forces scratch spills.
__global__ __launch_bounds__(256) void dwconv_k(const float* __restrict__ x,
    const float* __restrict__ wv, const float* __restrict__ bias,
    float* __restrict__ y) {
  __shared__ float lds[4 * 66 * 72];  // 76 KB -> 2 blocks/CU via LDS anyway
  int tid = threadIdx.x;
  int t0 = blockIdx.x * 2;
  int bc = blockIdx.y;
  int c  = bc % C96;
  const float* xp = x + (size_t)bc * THW;

  float4 z4 = make_float4(0.f, 0.f, 0.f, 0.f);
  for (int i = tid; i < 4752; i += 256) ((float4*)lds)[i] = z4;
  __syncthreads();
  for (int p = 0; p < 4; ++p) {
    int tt = t0 - 1 + p;
    if (tt < 0 || tt > 15) continue;
    const float* pp = xp + tt * HW;
    for (int i = tid; i < 1024; i += 256) {
      int row = i >> 4, c4 = i & 15;
      float4 v = *(const float4*)(pp + row * 64 + c4 * 4);
      *(float4*)&lds[(p * 66 + row + 1) * 72 + 4 + c4 * 4] = v;
    }
  }
  float w27[27];
#pragma unroll
  for (int i = 0; i < 27; ++i) w27[i] = wv[c * 27 + i];
  float bv = bias[c];
  __syncthreads();

  int s   = tid & 7;
  int tc  = (tid >> 3) & 1;
  int seg = tid >> 4;
  int h0 = seg * 4;
  int cb = 3 + 8 * s;

  float win[3][3][10];
#define LOADROW(q, slot, ldsrow) { \
    const float* rp = &lds[(((tc) + (q)) * 66 + (ldsrow)) * 72 + cb]; \
    _Pragma("unroll") for (int j = 0; j < 10; ++j) win[q][slot][j] = rp[j]; }

#pragma unroll
  for (int q = 0; q < 3; ++q) { LOADROW(q, 0, h0); LOADROW(q, 1, h0 + 1); }

  float* yp = y + (size_t)bc * THW + (t0 + tc) * HW + s * 8;
#pragma unroll
  for (int st = 0; st < 4; ++st) {
    int h = h0 + st;
#pragma unroll
    for (int q = 0; q < 3; ++q) { LOADROW(q, (st + 2) % 3, h + 2); }
    float acc[8];
#pragma unroll
    for (int w = 0; w < 8; ++w) acc[w] = bv;
#pragma unroll
    for (int q = 0; q < 3; ++q)
#pragma unroll
      for (int rr = 0; rr < 3; ++rr) {
        const float* row = win[q][(st + rr) % 3];
#pragma unroll
        for (int dw = 0; dw < 3; ++dw) {
          float coef = w27[q * 9 + rr * 3 + dw];
#pragma unroll
          for (int w = 0; w < 8; ++w) acc[w] = fmaf(row[w + dw], coef, acc[w]);
        }
      }
    *(float4*)&yp[h * 64]     = make_float4(acc[0], acc[1], acc[2], acc[3]);
    *(float4*)&yp[h * 64 + 4] = make_float4(acc[4], acc[5], acc[6], acc[7]);
  }
#undef LOADROW
}

// ---------------- fe transpose: [THW][96] -> [96][THW] -----------------------
__global__ __launch_bounds__(256) void feT_k(const float* __restrict__ fe,
                                             float* __restrict__ feT) {
  __shared__ float t[96 * 65];
  int tid = threadIdx.x;
  int tok0 = blockIdx.x * 64;
  const float* p = fe + (size_t)tok0 * 96;
  for (int i = tid; i < 6144; i += 256) {
    int tok = i / 96;
    int ch = i - tok * 96;
    t[ch * 65 + tok] = p[i];
  }
  __syncthreads();
  for (int i = tid; i < 6144; i += 256) {
    int ch = i >> 6, tok = i & 63;
    feT[(size_t)ch * THW + tok0 + tok] = t[ch * 65 + tok];
  }
}

// ---------------- LDS-staged 96xN GEMM family --------------------------------
// Out[co][n] = sum_k W[co][k] * In[k][n]  (+ epilogue)
// EPI 0: + bias, plain store
// EPI 1: tau: t=acc; tau=gelu(t); write A,B spectral maps
// EPI 2: LN+SiLU-gate applied to In at STAGING time (k-loop is pure GEMM)
#define FMA4(A, WV) \
  A.x = fmaf(WV, v.x, A.x); A.y = fmaf(WV, v.y, A.y); \
  A.z = fmaf(WV, v.z, A.z); A.w = fmaf(WV, v.w, A.w);

#define WPAD 104
#define BK32 32

template <int EPI>
__global__ __launch_bounds__(256) void gemm96_k(
    const float* __restrict__ In, const float* __restrict__ W,
    const float* __restrict__ bias, float* __restrict__ Out,
    float* __restrict__ Out2, const float* __restrict__ zg,
    const float* __restrict__ lnG, const float* __restrict__ lnB,
    const float* __restrict__ scal_c, const float* __restrict__ scal_a,
    int N, size_t inStride, size_t outStride) {
  __shared__ float Wt[96 * WPAD];      // [k][co], padded row (39 KB)
  __shared__ float buf[BK32 * 256];    // 32 KB
  int tid = threadIdx.x;
  int wvi = tid >> 6, ln = tid & 63;
  // conflict-free transposed fill: consecutive lanes -> consecutive co
  for (int i = tid; i < 2304; i += 256) {
    int k4 = i / 96, co = i - k4 * 96;
    float4 w4 = *(const float4*)(W + co * 96 + k4 * 4);
    int k = k4 * 4;
    Wt[(k + 0) * WPAD + co] = w4.x;
    Wt[(k + 1) * WPAD + co] = w4.y;
    Wt[(k + 2) * WPAD + co] = w4.z;
    Wt[(k + 3) * WPAD + co] = w4.w;
  }
  int tok_g = ln;
  int n0 = blockIdx.x * 256 + tok_g * 4;
  int co0 = wvi * 24;
  const float* ipb = In + blockIdx.y * inStride + blockIdx.x * 256 + ln * 4;
  const float* zpb = (EPI == 2) ? (zg + blockIdx.y * inStride + blockIdx.x * 256 + ln * 4)
                                : nullptr;

  float4 mu4, rs4;
  if (EPI == 2) {   // per-token LN stats for this lane's 4 tokens
    float4 sum = make_float4(0.f, 0.f, 0.f, 0.f);
    float4 sq  = make_float4(0.f, 0.f, 0.f, 0.f);
#pragma unroll 8
    for (int ci = 0; ci < 96; ++ci) {
      float4 t = *(const float4*)(ipb + (size_t)ci * N);
      sum.x += t.x; sum.y += t.y; sum.z += t.z; sum.w += t.w;
      sq.x = fmaf(t.x, t.x, sq.x); sq.y = fmaf(t.y, t.y, sq.y);
      sq.z = fmaf(t.z, t.z, sq.z); sq.w = fmaf(t.w, t.w, sq.w);
    }
    const float r96 = 1.0f / 96.0f;
    mu4.x = sum.x * r96; mu4.y = sum.y * r96; mu4.z = sum.z * r96; mu4.w = sum.w * r96;
    rs4.x = rsqrtf(fmaxf(sq.x * r96 - mu4.x * mu4.x, 0.f) + 1e-5f);
    rs4.y = rsqrtf(fmaxf(sq.y * r96 - mu4.y * mu4.y, 0.f) + 1e-5f);
    rs4.z = rsqrtf(fmaxf(sq.z * r96 - mu4.z * mu4.z, 0.f) + 1e-5f);
    rs4.w = rsqrtf(fmaxf(sq.w * r96 - mu4.w * mu4.w, 0.f) + 1e-5f);
  }

  float4 acc[24];
#pragma unroll
  for (int j = 0; j < 24; ++j) {
    float bj = bias[co0 + j];
    acc[j] = make_float4(bj, bj, bj, bj);
  }

  constexpr int NT  = 96 / BK32;
  constexpr int RPW = BK32 / 4;   // 8 rows staged per wave per tile
#pragma unroll 1
  for (int kb = 0; kb < NT; ++kb) {
    // stage tile kb (transient registers only)
#pragma unroll
    for (int i = 0; i < RPW; ++i) {
      int r = i * 4 + wvi;
      int k = kb * BK32 + r;
      float4 v4 = *(const float4*)(ipb + (size_t)k * N);
      if (EPI == 2) {
        float4 zz = *(const float4*)(zpb + (size_t)k * N);
        float lgk = lnG[k], lbk = lnB[k];
        float gx = zz.x * __builtin_amdgcn_rcpf(1.0f + __expf(-zz.x));
        float gy = zz.y * __builtin_amdgcn_rcpf(1.0f + __expf(-zz.y));
        float gz = zz.z * __builtin_amdgcn_rcpf(1.0f + __expf(-zz.z));
        float gw = zz.w * __builtin_amdgcn_rcpf(1.0f + __expf(-zz.w));
        v4.x = fmaf((v4.x - mu4.x) * rs4.x, lgk, lbk) * gx;
        v4.y = fmaf((v4.y - mu4.y) * rs4.y, lgk, lbk) * gy;
        v4.z = fmaf((v4.z - mu4.z) * rs4.z, lgk, lbk) * gz;
        v4.w = fmaf((v4.w - mu4.w) * rs4.w, lgk, lbk) * gw;
      }
      *(float4*)&buf[r * 256 + ln * 4] = v4;
    }
    __syncthreads();
    // moderate unroll: keeps scheduler register demand bounded (no spills)
#pragma unroll 8
    for (int kk = 0; kk < BK32; ++kk) {
      int k = kb * BK32 + kk;
      float4 v = *(const float4*)&buf[kk * 256 + tok_g * 4];
      const float4* wr = (const float4*)&Wt[k * WPAD + co0];
#pragma unroll
      for (int j = 0; j < 6; ++j) {
        float4 wvv = wr[j];
        FMA4(acc[4 * j + 0], wvv.x);
        FMA4(acc[4 * j + 1], wvv.y);
        FMA4(acc[4 * j + 2], wvv.z);
        FMA4(acc[4 * j + 3], wvv.w);
      }
    }
    __syncthreads();
  }

  if (EPI == 1) {
    float cv = scal_c[0], al = scal_a[0];
    float rc = 1.0f / (cv + 1e-8f);
#define TAUMAP(T, AA, BB) { \
    float tau = 0.5f * (T) * (1.0f + erff((T) * 0.70710678118654752f)); \
    float ct = cv * tau; \
    float damp = __expf(-0.5f * al * tau); \
    float sc = __sinf(ct), cc = __cosf(ct); \
    AA = damp * (cc + sc * al * 0.5f * rc); BB = damp * sc * rc; }
#pragma unroll 2
    for (int j = 0; j < 24; ++j) {
      float4 a4, b4;
      TAUMAP(acc[j].x, a4.x, b4.x);
      TAUMAP(acc[j].y, a4.y, b4.y);
      TAUMAP(acc[j].z, a4.z, b4.z);
      TAUMAP(acc[j].w, a4.w, b4.w);
      *(float4*)(Out  + (size_t)(co0 + j) * N + n0) = a4;
      *(float4*)(Out2 + (size_t)(co0 + j) * N + n0) = b4;
    }
#undef TAUMAP
  } else {
    float* op = Out + blockIdx.y * outStride + n0;
#pragma unroll
    for (int j = 0; j < 24; ++j)
      *(float4*)(op + (size_t)(co0 + j) * N) = acc[j];
  }
}

// ---------------- fused W+H (I)DCT on one 64x64 plane ------------------------
template <bool DCT>
__global__ __launch_bounds__(256) void wh_k(const float* __restrict__ in,
    float* __restrict__ out, const float* __restrict__ b64) {
  __shared__ float XT[64 * 68];
  __shared__ float Yb[64 * 68];
  __shared__ float Bs[64 * 68];
  int tid = threadIdx.x;
  const float* ip = in + (size_t)blockIdx.x * HW;
  float* op = out + (size_t)blockIdx.x * HW;
  for (int i = tid; i < 4096; i += 256) {
    int r = i >> 6, cdx = i & 63;
    Bs[r * 68 + cdx] = DCT ? b64[cdx * 64 + r] : b64[r * 64 + cdx];
  }
  for (int i = tid; i < 4096; i += 256) {
    int h = i >> 6, w = i & 63;
    XT[w * 68 + h] = ip[i];
  }
  __syncthreads();
  int n = tid & 63;
  int g = tid >> 6;
  {
    float acc[16];
#pragma unroll
    for (int i = 0; i < 16; ++i) acc[i] = 0.0f;
#pragma unroll 4
    for (int w = 0; w < 64; ++w) {
      float bv = Bs[w * 68 + n];
      const float4* xw = (const float4*)&XT[w * 68 + g * 16];
      float4 x0 = xw[0], x1 = xw[1], x2 = xw[2], x3 = xw[3];
      acc[0]  += x0.x * bv; acc[1]  += x0.y * bv; acc[2]  += x0.z * bv; acc[3]  += x0.w * bv;
      acc[4]  += x1.x * bv; acc[5]  += x1.y * bv; acc[6]  += x1.z * bv; acc[7]  += x1.w * bv;
      acc[8]  += x2.x * bv; acc[9]  += x2.y * bv; acc[10] += x2.z * bv; acc[11] += x2.w * bv;
      acc[12] += x3.x * bv; acc[13] += x3.y * bv; acc[14] += x3.z * bv; acc[15] += x3.w * bv;
    }
#pragma unroll
    for (int i = 0; i < 16; ++i) Yb[(g * 16 + i) * 68 + n] = acc[i];
  }
  __syncthreads();
  {
    float acc[16];
#pragma unroll
    for (int i = 0; i < 16; ++i) acc[i] = 0.0f;
#pragma unroll 4
    for (int h = 0; h < 64; ++h) {
      float yv = Yb[h * 68 + n];
      const float4* bw = (const float4*)&Bs[h * 68 + g * 16];
      float4 b0 = bw[0], b1 = bw[1], b2 = bw[2], b3 = bw[3];
      acc[0]  += b0.x * yv; acc[1]  += b0.y * yv; acc[2]  += b0.z * yv; acc[3]  += b0.w * yv;
      acc[4]  += b1.x * yv; acc[5]  += b1.y * yv; acc[6]  += b1.z * yv; acc[7]  += b1.w * yv;
      acc[8]  += b2.x * yv; acc[9]  += b2.y * yv; acc[10] += b2.z * yv; acc[11] += b2.w * yv;
      acc[12] += b3.x * yv; acc[13] += b3.y * yv; acc[14] += b3.z * yv; acc[15] += b3.w * yv;
    }
#pragma unroll
    for (int i = 0; i < 16; ++i) op[(g * 16 + i) * 64 + n] = acc[i];
  }
}

// ---------------- fused T-DCT + spectral multiply + T-IDCT -------------------
__global__ __launch_bounds__(256) void tspec_k(const float* __restrict__ U0,
    const float* __restrict__ V0, const float* __restrict__ A,
    const float* __restrict__ Bc, const float* __restrict__ b16,
    float* __restrict__ out) {
  __shared__ float bs[256];
  int tid = threadIdx.x;
  bs[tid] = b16[tid];
  __syncthreads();
  int hw = blockIdx.x * 256 + tid;
  int c = blockIdx.y, b = blockIdx.z;
  size_t base = ((size_t)(b * C96 + c) * 16) * HW + hw;
  int cbase = c * THW + hw;
  float u[16], v[16];
#pragma unroll
  for (int t = 0; t < 16; ++t) { u[t] = U0[base + t * HW]; v[t] = V0[base + t * HW]; }
  float so[16];
#pragma unroll
  for (int n = 0; n < 16; ++n) {
    float ua = 0.0f, va = 0.0f;
#pragma unroll
    for (int t = 0; t < 16; ++t) { float bb = bs[n * 16 + t]; ua += bb * u[t]; va += bb * v[t]; }
    so[n] = A[cbase + n * HW] * ua + Bc[cbase + n * HW] * va;
  }
#pragma unroll
  for (int t = 0; t < 16; ++t) {
    float acc = 0.0f;
#pragma unroll
    for (int n = 0; n < 16; ++n) acc += so[n] * bs[n * 16 + t];
    out[base + t * HW] = acc;
  }
}

extern "C" void kernel_launch(void* const* d_in, const int* in_sizes, int n_in,
                              void* d_out, int out_size, void* d_ws, size_t ws_size,
                              hipStream_t stream) {
  const float* x    = (const float*)d_in[0];
  const float* fe   = (const float*)d_in[1];
  const float* dww  = (const float*)d_in[2];
  const float* dwb  = (const float*)d_in[3];
  const float* linW = (const float*)d_in[4];
  const float* linB = (const float*)d_in[5];
  const float* v0W  = (const float*)d_in[6];
  const float* v0B  = (const float*)d_in[7];
  const float* tokW = (const float*)d_in[8];
  const float* tokB = (const float*)d_in[9];
  const float* cS   = (const float*)d_in[10];
  const float* aS   = (const float*)d_in[11];
  const float* lnG  = (const float*)d_in[12];
  const float* lnBp = (const float*)d_in[13];
  const float* outW = (const float*)d_in[14];
  const float* outB = (const float*)d_in[15];
  float* out = (float*)d_out;

  float* w = (float*)d_ws;
  const size_t TEN = (size_t)2 * C96 * THW;
  const size_t BST = (size_t)C96 * THW;
  float* b64    = w;
  float* b16    = w + 4096;
  float* buf_y  = w + 8192;
  float* buf_xg = buf_y + TEN;
  float* buf_z  = buf_xg + TEN;
  float* buf_v0 = buf_z + TEN;
  float* bufA   = buf_v0 + TEN;
  float* bufB   = bufA + BST;
  size_t need = (size_t)(8192 + 4 * TEN + 2 * BST) * sizeof(float);
  if (ws_size < need) return;

  hipLaunchKernelGGL(init_basis_k, dim3(1), dim3(256), 0, stream, b64, b16);
  hipLaunchKernelGGL(dwconv_k, dim3(8, 192), dim3(256), 0, stream, x, dww, dwb, buf_y);
  hipLaunchKernelGGL((gemm96_k<0>), dim3(256, 2), dim3(256), 0, stream,
                     buf_y, linW, linB, buf_xg, (float*)nullptr, (const float*)nullptr,
                     (const float*)nullptr, (const float*)nullptr,
                     (const float*)nullptr, (const float*)nullptr, THW, BST, BST);
  hipLaunchKernelGGL((gemm96_k<0>), dim3(256, 2), dim3(256), 0, stream,
                     buf_y, linW + 9216, linB + 96, buf_z, (float*)nullptr, (const float*)nullptr,
                     (const float*)nullptr, (const float*)nullptr,
                     (const float*)nullptr, (const float*)nullptr, THW, BST, BST);
  hipLaunchKernelGGL(feT_k, dim3(1024), dim3(256), 0, stream, fe, buf_v0);
  hipLaunchKernelGGL((gemm96_k<1>), dim3(256, 1), dim3(256), 0, stream,
                     buf_v0, tokW, tokB, bufA, bufB, (const float*)nullptr,
                     (const float*)nullptr, (const float*)nullptr,
                     cS, aS, THW, (size_t)0, (size_t)0);
  hipLaunchKernelGGL((gemm96_k<0>), dim3(256, 2), dim3(256), 0, stream,
                     buf_xg, v0W, v0B, buf_v0, (float*)nullptr, (const float*)nullptr,
                     (const float*)nullptr, (const float*)nullptr,
                     (const float*)nullptr, (const float*)nullptr, THW, BST, BST);
  hipLaunchKernelGGL(wh_k<true>, dim3(3072), dim3(256), 0, stream, buf_xg, buf_y, b64);
  hipLaunchKernelGGL(wh_k<true>, dim3(3072), dim3(256), 0, stream, buf_v0, buf_xg, b64);
  hipLaunchKernelGGL(tspec_k, dim3(16, 96, 2), dim3(256), 0, stream, buf_y, buf_xg, bufA, bufB, b16, buf_v0);
  hipLaunchKernelGGL(wh_k<false>, dim3(3072), dim3(256), 0, stream, buf_v0, buf_y, b64);
  hipLaunchKernelGGL((gemm96_k<2>), dim3(256, 2), dim3(256), 0, stream,
                     buf_y, outW, outB, out, (float*)nullptr, buf_z,
                     lnG, lnBp, (const float*)nullptr, (const float*)nullptr, THW, BST, BST);
}

// Round 6
// 663.755 us; speedup vs baseline: 1.4977x; 1.0734x over previous
//
#include <hip/hip_runtime.h>
#include <math.h>

#define THW 65536
#define HW  4096
#define C96 96
#ifndef M_PI
#define M_PI 3.14159265358979323846
#endif

// ---------------- basis init (once per launch; ws is re-poisoned each call) --
// b64[n*64+x] = C[n][x];  b64T[x*64+n] = C[n][x]  (transposed copy)
__global__ __launch_bounds__(256) void init_basis_k(float* __restrict__ b64,
                                                    float* __restrict__ b64T,
                                                    float* __restrict__ b16) {
  int tid = threadIdx.x;
  for (int i = tid; i < 4096; i += 256) {
    int n = i >> 6, x = i & 63;
    double s = sqrt(2.0 / 64.0) * (n == 0 ? sqrt(0.5) : 1.0);
    float v = (float)(cos((double)n * ((double)x + 0.5) * M_PI / 64.0) * s);
    b64[i] = v;
    b64T[x * 64 + n] = v;
  }
  {
    int n = tid >> 4, x = tid & 15;
    double s = sqrt(2.0 / 16.0) * (n == 0 ? sqrt(0.5) : 1.0);
    b16[tid & 255] = (float)(cos((double)n * ((double)x + 0.5) * M_PI / 16.0) * s);
  }
}

// ---------------- depthwise 3x3x3 conv: LDS planes + sliding h-window --------
__global__ __launch_bounds__(256) void dwconv_k(const float* __restrict__ x,
    const float* __restrict__ wv, const float* __restrict__ bias,
    float* __restrict__ y) {
  __shared__ float lds[4 * 66 * 72];  // 76 KB -> 2 blocks/CU via LDS
  int tid = threadIdx.x;
  int t0 = blockIdx.x * 2;
  int bc = blockIdx.y;
  int c  = bc % C96;
  const float* xp = x + (size_t)bc * THW;

  float4 z4 = make_float4(0.f, 0.f, 0.f, 0.f);
  for (int i = tid; i < 4752; i += 256) ((float4*)lds)[i] = z4;
  __syncthreads();
  for (int p = 0; p < 4; ++p) {
    int tt = t0 - 1 + p;
    if (tt < 0 || tt > 15) continue;
    const float* pp = xp + tt * HW;
    for (int i = tid; i < 1024; i += 256) {
      int row = i >> 4, c4 = i & 15;
      float4 v = *(const float4*)(pp + row * 64 + c4 * 4);
      *(float4*)&lds[(p * 66 + row + 1) * 72 + 4 + c4 * 4] = v;
    }
  }
  float w27[27];
#pragma unroll
  for (int i = 0; i < 27; ++i) w27[i] = wv[c * 27 + i];
  float bv = bias[c];
  __syncthreads();

  int s   = tid & 7;
  int tc  = (tid >> 3) & 1;
  int seg = tid >> 4;
  int h0 = seg * 4;
  int cb = 3 + 8 * s;

  float win[3][3][10];
#define LOADROW(q, slot, ldsrow) { \
    const float* rp = &lds[(((tc) + (q)) * 66 + (ldsrow)) * 72 + cb]; \
    _Pragma("unroll") for (int j = 0; j < 10; ++j) win[q][slot][j] = rp[j]; }

#pragma unroll
  for (int q = 0; q < 3; ++q) { LOADROW(q, 0, h0); LOADROW(q, 1, h0 + 1); }

  float* yp = y + (size_t)bc * THW + (t0 + tc) * HW + s * 8;
#pragma unroll
  for (int st = 0; st < 4; ++st) {
    int h = h0 + st;
#pragma unroll
    for (int q = 0; q < 3; ++q) { LOADROW(q, (st + 2) % 3, h + 2); }
    float acc[8];
#pragma unroll
    for (int w = 0; w < 8; ++w) acc[w] = bv;
#pragma unroll
    for (int q = 0; q < 3; ++q)
#pragma unroll
      for (int rr = 0; rr < 3; ++rr) {
        const float* row = win[q][(st + rr) % 3];
#pragma unroll
        for (int dw = 0; dw < 3; ++dw) {
          float coef = w27[q * 9 + rr * 3 + dw];
#pragma unroll
          for (int w = 0; w < 8; ++w) acc[w] = fmaf(row[w + dw], coef, acc[w]);
        }
      }
    *(float4*)&yp[h * 64]     = make_float4(acc[0], acc[1], acc[2], acc[3]);
    *(float4*)&yp[h * 64 + 4] = make_float4(acc[4], acc[5], acc[6], acc[7]);
  }
#undef LOADROW
}

// ---------------- fe transpose: [THW][96] -> [96][THW] -----------------------
__global__ __launch_bounds__(256) void feT_k(const float* __restrict__ fe,
                                             float* __restrict__ feT) {
  __shared__ float t[96 * 65];
  int tid = threadIdx.x;
  int tok0 = blockIdx.x * 64;
  const float* p = fe + (size_t)tok0 * 96;
  for (int i = tid; i < 6144; i += 256) {
    int tok = i / 96;
    int ch = i - tok * 96;
    t[ch * 65 + tok] = p[i];
  }
  __syncthreads();
  for (int i = tid; i < 6144; i += 256) {
    int ch = i >> 6, tok = i & 63;
    feT[(size_t)ch * THW + tok0 + tok] = t[ch * 65 + tok];
  }
}

// ---------------- LDS-staged 96xN GEMM family --------------------------------
#define FMA4(A, WV) \
  A.x = fmaf(WV, v.x, A.x); A.y = fmaf(WV, v.y, A.y); \
  A.z = fmaf(WV, v.z, A.z); A.w = fmaf(WV, v.w, A.w);

#define WPAD 104
#define BK32 32

template <int EPI>
__global__ __launch_bounds__(256) void gemm96_k(
    const float* __restrict__ In, const float* __restrict__ W,
    const float* __restrict__ bias, float* __restrict__ Out,
    float* __restrict__ Out2, const float* __restrict__ zg,
    const float* __restrict__ lnG, const float* __restrict__ lnB,
    const float* __restrict__ scal_c, const float* __restrict__ scal_a,
    int N, size_t inStride, size_t outStride) {
  __shared__ float Wt[96 * WPAD];      // [k][co], padded row (39 KB)
  __shared__ float buf[BK32 * 256];    // 32 KB
  int tid = threadIdx.x;
  int wvi = tid >> 6, ln = tid & 63;
  for (int i = tid; i < 2304; i += 256) {
    int k4 = i / 96, co = i - k4 * 96;
    float4 w4 = *(const float4*)(W + co * 96 + k4 * 4);
    int k = k4 * 4;
    Wt[(k + 0) * WPAD + co] = w4.x;
    Wt[(k + 1) * WPAD + co] = w4.y;
    Wt[(k + 2) * WPAD + co] = w4.z;
    Wt[(k + 3) * WPAD + co] = w4.w;
  }
  int tok_g = ln;
  int n0 = blockIdx.x * 256 + tok_g * 4;
  int co0 = wvi * 24;
  const float* ipb = In + blockIdx.y * inStride + blockIdx.x * 256 + ln * 4;
  const float* zpb = (EPI == 2) ? (zg + blockIdx.y * inStride + blockIdx.x * 256 + ln * 4)
                                : nullptr;

  float4 mu4, rs4;
  if (EPI == 2) {
    float4 sum = make_float4(0.f, 0.f, 0.f, 0.f);
    float4 sq  = make_float4(0.f, 0.f, 0.f, 0.f);
#pragma unroll 8
    for (int ci = 0; ci < 96; ++ci) {
      float4 t = *(const float4*)(ipb + (size_t)ci * N);
      sum.x += t.x; sum.y += t.y; sum.z += t.z; sum.w += t.w;
      sq.x = fmaf(t.x, t.x, sq.x); sq.y = fmaf(t.y, t.y, sq.y);
      sq.z = fmaf(t.z, t.z, sq.z); sq.w = fmaf(t.w, t.w, sq.w);
    }
    const float r96 = 1.0f / 96.0f;
    mu4.x = sum.x * r96; mu4.y = sum.y * r96; mu4.z = sum.z * r96; mu4.w = sum.w * r96;
    rs4.x = rsqrtf(fmaxf(sq.x * r96 - mu4.x * mu4.x, 0.f) + 1e-5f);
    rs4.y = rsqrtf(fmaxf(sq.y * r96 - mu4.y * mu4.y, 0.f) + 1e-5f);
    rs4.z = rsqrtf(fmaxf(sq.z * r96 - mu4.z * mu4.z, 0.f) + 1e-5f);
    rs4.w = rsqrtf(fmaxf(sq.w * r96 - mu4.w * mu4.w, 0.f) + 1e-5f);
  }

  float4 acc[24];
#pragma unroll
  for (int j = 0; j < 24; ++j) {
    float bj = bias[co0 + j];
    acc[j] = make_float4(bj, bj, bj, bj);
  }

  constexpr int NT  = 96 / BK32;
  constexpr int RPW = BK32 / 4;
#pragma unroll 1
  for (int kb = 0; kb < NT; ++kb) {
#pragma unroll
    for (int i = 0; i < RPW; ++i) {
      int r = i * 4 + wvi;
      int k = kb * BK32 + r;
      float4 v4 = *(const float4*)(ipb + (size_t)k * N);
      if (EPI == 2) {
        float4 zz = *(const float4*)(zpb + (size_t)k * N);
        float lgk = lnG[k], lbk = lnB[k];
        float gx = zz.x * __builtin_amdgcn_rcpf(1.0f + __expf(-zz.x));
        float gy = zz.y * __builtin_amdgcn_rcpf(1.0f + __expf(-zz.y));
        float gz = zz.z * __builtin_amdgcn_rcpf(1.0f + __expf(-zz.z));
        float gw = zz.w * __builtin_amdgcn_rcpf(1.0f + __expf(-zz.w));
        v4.x = fmaf((v4.x - mu4.x) * rs4.x, lgk, lbk) * gx;
        v4.y = fmaf((v4.y - mu4.y) * rs4.y, lgk, lbk) * gy;
        v4.z = fmaf((v4.z - mu4.z) * rs4.z, lgk, lbk) * gz;
        v4.w = fmaf((v4.w - mu4.w) * rs4.w, lgk, lbk) * gw;
      }
      *(float4*)&buf[r * 256 + ln * 4] = v4;
    }
    __syncthreads();
#pragma unroll 8
    for (int kk = 0; kk < BK32; ++kk) {
      int k = kb * BK32 + kk;
      float4 v = *(const float4*)&buf[kk * 256 + tok_g * 4];
      const float4* wr = (const float4*)&Wt[k * WPAD + co0];
#pragma unroll
      for (int j = 0; j < 6; ++j) {
        float4 wvv = wr[j];
        FMA4(acc[4 * j + 0], wvv.x);
        FMA4(acc[4 * j + 1], wvv.y);
        FMA4(acc[4 * j + 2], wvv.z);
        FMA4(acc[4 * j + 3], wvv.w);
      }
    }
    __syncthreads();
  }

  if (EPI == 1) {
    float cv = scal_c[0], al = scal_a[0];
    float rc = 1.0f / (cv + 1e-8f);
#define TAUMAP(T, AA, BB) { \
    float tau = 0.5f * (T) * (1.0f + erff((T) * 0.70710678118654752f)); \
    float ct = cv * tau; \
    float damp = __expf(-0.5f * al * tau); \
    float sc = __sinf(ct), cc = __cosf(ct); \
    AA = damp * (cc + sc * al * 0.5f * rc); BB = damp * sc * rc; }
#pragma unroll 2
    for (int j = 0; j < 24; ++j) {
      float4 a4, b4;
      TAUMAP(acc[j].x, a4.x, b4.x);
      TAUMAP(acc[j].y, a4.y, b4.y);
      TAUMAP(acc[j].z, a4.z, b4.z);
      TAUMAP(acc[j].w, a4.w, b4.w);
      *(float4*)(Out  + (size_t)(co0 + j) * N + n0) = a4;
      *(float4*)(Out2 + (size_t)(co0 + j) * N + n0) = b4;
    }
#undef TAUMAP
  } else {
    float* op = Out + blockIdx.y * outStride + n0;
#pragma unroll
    for (int j = 0; j < 24; ++j)
      *(float4*)(op + (size_t)(co0 + j) * N) = acc[j];
  }
}

// ---------------- fused W+H (I)DCT, 4x4 register-tiled -----------------------
// basis = b64T for DCT (Bs[w][n]=C[n][w]), b64 for IDCT (Bs[w][n]=C[w][n]).
// step1: Y[h][n] = sum_w XT[w][h]*Bs[w][n]; step2: Z[m][n] = sum_h Bs[h][m]*Y[h][n]
// Each thread: 4 rows x 4 cols -> 16 FMA per 2 ds_read_b128 (2 B/FLOP).
__global__ __launch_bounds__(256) void wh_k(const float* __restrict__ in,
    float* __restrict__ out, const float* __restrict__ basis) {
  __shared__ float XT[64 * 68];
  __shared__ float Yb[64 * 68];
  __shared__ float Bs[64 * 68];
  int tid = threadIdx.x;
  const float* ip = in + (size_t)blockIdx.x * HW;
  float* op = out + (size_t)blockIdx.x * HW;
  // stage Bs coalesced (basis rows already in the orientation we consume)
  for (int i = tid; i < 1024; i += 256) {
    int r = i >> 4, c4 = i & 15;
    float4 v = *(const float4*)(basis + r * 64 + c4 * 4);
    *(float4*)&Bs[r * 68 + c4 * 4] = v;
  }
  // stage XT transposed: float4 global read, 4 scalar LDS stores
  for (int i = tid; i < 1024; i += 256) {
    int h = i >> 4, w4 = i & 15;
    float4 v = *(const float4*)(ip + h * 64 + w4 * 4);
    int w = w4 * 4;
    XT[(w + 0) * 68 + h] = v.x;
    XT[(w + 1) * 68 + h] = v.y;
    XT[(w + 2) * 68 + h] = v.z;
    XT[(w + 3) * 68 + h] = v.w;
  }
  __syncthreads();
  int nb = tid & 15, rb = tid >> 4;
  int n0 = nb * 4, r0 = rb * 4;
  {
    float4 a0 = make_float4(0.f, 0.f, 0.f, 0.f), a1 = a0, a2 = a0, a3 = a0;
#pragma unroll 8
    for (int w = 0; w < 64; ++w) {
      float4 xv = *(const float4*)&XT[w * 68 + r0];  // X[r0..r0+3][w]
      float4 bv = *(const float4*)&Bs[w * 68 + n0];  // Bs[w][n0..n0+3]
      a0.x = fmaf(xv.x, bv.x, a0.x); a0.y = fmaf(xv.x, bv.y, a0.y);
      a0.z = fmaf(xv.x, bv.z, a0.z); a0.w = fmaf(xv.x, bv.w, a0.w);
      a1.x = fmaf(xv.y, bv.x, a1.x); a1.y = fmaf(xv.y, bv.y, a1.y);
      a1.z = fmaf(xv.y, bv.z, a1.z); a1.w = fmaf(xv.y, bv.w, a1.w);
      a2.x = fmaf(xv.z, bv.x, a2.x); a2.y = fmaf(xv.z, bv.y, a2.y);
      a2.z = fmaf(xv.z, bv.z, a2.z); a2.w = fmaf(xv.z, bv.w, a2.w);
      a3.x = fmaf(xv.w, bv.x, a3.x); a3.y = fmaf(xv.w, bv.y, a3.y);
      a3.z = fmaf(xv.w, bv.z, a3.z); a3.w = fmaf(xv.w, bv.w, a3.w);
    }
    *(float4*)&Yb[(r0 + 0) * 68 + n0] = a0;
    *(float4*)&Yb[(r0 + 1) * 68 + n0] = a1;
    *(float4*)&Yb[(r0 + 2) * 68 + n0] = a2;
    *(float4*)&Yb[(r0 + 3) * 68 + n0] = a3;
  }
  __syncthreads();
  {
    float4 a0 = make_float4(0.f, 0.f, 0.f, 0.f), a1 = a0, a2 = a0, a3 = a0;
#pragma unroll 8
    for (int h = 0; h < 64; ++h) {
      float4 bv = *(const float4*)&Bs[h * 68 + r0];  // Bs[h][m0..m0+3]
      float4 yv = *(const float4*)&Yb[h * 68 + n0];  // Y[h][n0..n0+3]
      a0.x = fmaf(bv.x, yv.x, a0.x); a0.y = fmaf(bv.x, yv.y, a0.y);
      a0.z = fmaf(bv.x, yv.z, a0.z); a0.w = fmaf(bv.x, yv.w, a0.w);
      a1.x = fmaf(bv.y, yv.x, a1.x); a1.y = fmaf(bv.y, yv.y, a1.y);
      a1.z = fmaf(bv.y, yv.z, a1.z); a1.w = fmaf(bv.y, yv.w, a1.w);
      a2.x = fmaf(bv.z, yv.x, a2.x); a2.y = fmaf(bv.z, yv.y, a2.y);
      a2.z = fmaf(bv.z, yv.z, a2.z); a2.w = fmaf(bv.z, yv.w, a2.w);
      a3.x = fmaf(bv.w, yv.x, a3.x); a3.y = fmaf(bv.w, yv.y, a3.y);
      a3.z = fmaf(bv.w, yv.z, a3.z); a3.w = fmaf(bv.w, yv.w, a3.w);
    }
    *(float4*)&op[(r0 + 0) * 64 + n0] = a0;
    *(float4*)&op[(r0 + 1) * 64 + n0] = a1;
    *(float4*)&op[(r0 + 2) * 64 + n0] = a2;
    *(float4*)&op[(r0 + 3) * 64 + n0] = a3;
  }
}

// ---------------- fused T-DCT + spectral multiply + T-IDCT -------------------
__global__ __launch_bounds__(256) void tspec_k(const float* __restrict__ U0,
    const float* __restrict__ V0, const float* __restrict__ A,
    const float* __restrict__ Bc, const float* __restrict__ b16,
    float* __restrict__ out) {
  __shared__ float bs[256];
  int tid = threadIdx.x;
  bs[tid] = b16[tid];
  __syncthreads();
  int hw = blockIdx.x * 256 + tid;
  int c = blockIdx.y, b = blockIdx.z;
  size_t base = ((size_t)(b * C96 + c) * 16) * HW + hw;
  int cbase = c * THW + hw;
  float u[16], v[16];
#pragma unroll
  for (int t = 0; t < 16; ++t) { u[t] = U0[base + t * HW]; v[t] = V0[base + t * HW]; }
  float so[16];
#pragma unroll
  for (int n = 0; n < 16; ++n) {
    float ua = 0.0f, va = 0.0f;
#pragma unroll
    for (int t = 0; t < 16; ++t) { float bb = bs[n * 16 + t]; ua += bb * u[t]; va += bb * v[t]; }
    so[n] = A[cbase + n * HW] * ua + Bc[cbase + n * HW] * va;
  }
#pragma unroll
  for (int t = 0; t < 16; ++t) {
    float acc = 0.0f;
#pragma unroll
    for (int n = 0; n < 16; ++n) acc += so[n] * bs[n * 16 + t];
    out[base + t * HW] = acc;
  }
}

extern "C" void kernel_launch(void* const* d_in, const int* in_sizes, int n_in,
                              void* d_out, int out_size, void* d_ws, size_t ws_size,
                              hipStream_t stream) {
  const float* x    = (const float*)d_in[0];
  const float* fe   = (const float*)d_in[1];
  const float* dww  = (const float*)d_in[2];
  const float* dwb  = (const float*)d_in[3];
  const float* linW = (const float*)d_in[4];
  const float* linB = (const float*)d_in[5];
  const float* v0W  = (const float*)d_in[6];
  const float* v0B  = (const float*)d_in[7];
  const float* tokW = (const float*)d_in[8];
  const float* tokB = (const float*)d_in[9];
  const float* cS   = (const float*)d_in[10];
  const float* aS   = (const float*)d_in[11];
  const float* lnG  = (const float*)d_in[12];
  const float* lnBp = (const float*)d_in[13];
  const float* outW = (const float*)d_in[14];
  const float* outB = (const float*)d_in[15];
  float* out = (float*)d_out;

  float* w = (float*)d_ws;
  const size_t TEN = (size_t)2 * C96 * THW;
  const size_t BST = (size_t)C96 * THW;
  float* b64    = w;                 // 4096
  float* b64T   = w + 4096;          // 4096
  float* b16    = w + 8192;          // 256
  float* buf_y  = w + 16384;
  float* buf_xg = buf_y + TEN;
  float* buf_z  = buf_xg + TEN;
  float* buf_v0 = buf_z + TEN;
  float* bufA   = buf_v0 + TEN;
  float* bufB   = bufA + BST;
  size_t need = (size_t)(16384 + 4 * TEN + 2 * BST) * sizeof(float);
  if (ws_size < need) return;

  hipLaunchKernelGGL(init_basis_k, dim3(1), dim3(256), 0, stream, b64, b64T, b16);
  hipLaunchKernelGGL(dwconv_k, dim3(8, 192), dim3(256), 0, stream, x, dww, dwb, buf_y);
  hipLaunchKernelGGL((gemm96_k<0>), dim3(256, 2), dim3(256), 0, stream,
                     buf_y, linW, linB, buf_xg, (float*)nullptr, (const float*)nullptr,
                     (const float*)nullptr, (const float*)nullptr,
                     (const float*)nullptr, (const float*)nullptr, THW, BST, BST);
  hipLaunchKernelGGL((gemm96_k<0>), dim3(256, 2), dim3(256), 0, stream,
                     buf_y, linW + 9216, linB + 96, buf_z, (float*)nullptr, (const float*)nullptr,
                     (const float*)nullptr, (const float*)nullptr,
                     (const float*)nullptr, (const float*)nullptr, THW, BST, BST);
  hipLaunchKernelGGL(feT_k, dim3(1024), dim3(256), 0, stream, fe, buf_v0);
  hipLaunchKernelGGL((gemm96_k<1>), dim3(256, 1), dim3(256), 0, stream,
                     buf_v0, tokW, tokB, bufA, bufB, (const float*)nullptr,
                     (const float*)nullptr, (const float*)nullptr,
                     cS, aS, THW, (size_t)0, (size_t)0);
  hipLaunchKernelGGL((gemm96_k<0>), dim3(256, 2), dim3(256), 0, stream,
                     buf_xg, v0W, v0B, buf_v0, (float*)nullptr, (const float*)nullptr,
                     (const float*)nullptr, (const float*)nullptr,
                     (const float*)nullptr, (const float*)nullptr, THW, BST, BST);
  // DCT uses b64T; IDCT uses b64
  hipLaunchKernelGGL(wh_k, dim3(3072), dim3(256), 0, stream, buf_xg, buf_y, b64T);
  hipLaunchKernelGGL(wh_k, dim3(3072), dim3(256), 0, stream, buf_v0, buf_xg, b64T);
  hipLaunchKernelGGL(tspec_k, dim3(16, 96, 2), dim3(256), 0, stream, buf_y, buf_xg, bufA, bufB, b16, buf_v0);
  hipLaunchKernelGGL(wh_k, dim3(3072), dim3(256), 0, stream, buf_v0, buf_y, b64);
  hipLaunchKernelGGL((gemm96_k<2>), dim3(256, 2), dim3(256), 0, stream,
                     buf_y, outW, outB, out, (float*)nullptr, buf_z,
                     lnG, lnBp, (const float*)nullptr, (const float*)nullptr, THW, BST, BST);
}

// Round 7
// 629.149 us; speedup vs baseline: 1.5801x; 1.0550x over previous
//
#include <hip/hip_runtime.h>
#include <math.h>

#define THW 65536
#define HW  4096
#define C96 96
#ifndef M_PI
#define M_PI 3.14159265358979323846
#endif

// ---------------- basis init (once per launch; ws is re-poisoned each call) --
__global__ __launch_bounds__(256) void init_basis_k(float* __restrict__ b64,
                                                    float* __restrict__ b64T,
                                                    float* __restrict__ b16) {
  int tid = threadIdx.x;
  for (int i = tid; i < 4096; i += 256) {
    int n = i >> 6, x = i & 63;
    double s = sqrt(2.0 / 64.0) * (n == 0 ? sqrt(0.5) : 1.0);
    float v = (float)(cos((double)n * ((double)x + 0.5) * M_PI / 64.0) * s);
    b64[i] = v;
    b64T[x * 64 + n] = v;
  }
  {
    int n = tid >> 4, x = tid & 15;
    double s = sqrt(2.0 / 16.0) * (n == 0 ? sqrt(0.5) : 1.0);
    b16[tid & 255] = (float)(cos((double)n * ((double)x + 0.5) * M_PI / 16.0) * s);
  }
}

// ---------------- depthwise 3x3x3 conv: LDS planes + sliding h-window --------
__global__ __launch_bounds__(256) void dwconv_k(const float* __restrict__ x,
    const float* __restrict__ wv, const float* __restrict__ bias,
    float* __restrict__ y) {
  __shared__ float lds[4 * 66 * 72];  // 76 KB -> 2 blocks/CU via LDS
  int tid = threadIdx.x;
  int t0 = blockIdx.x * 2;
  int bc = blockIdx.y;
  int c  = bc % C96;
  const float* xp = x + (size_t)bc * THW;

  float4 z4 = make_float4(0.f, 0.f, 0.f, 0.f);
  for (int i = tid; i < 4752; i += 256) ((float4*)lds)[i] = z4;
  __syncthreads();
  for (int p = 0; p < 4; ++p) {
    int tt = t0 - 1 + p;
    if (tt < 0 || tt > 15) continue;
    const float* pp = xp + tt * HW;
    for (int i = tid; i < 1024; i += 256) {
      int row = i >> 4, c4 = i & 15;
      float4 v = *(const float4*)(pp + row * 64 + c4 * 4);
      *(float4*)&lds[(p * 66 + row + 1) * 72 + 4 + c4 * 4] = v;
    }
  }
  float w27[27];
#pragma unroll
  for (int i = 0; i < 27; ++i) w27[i] = wv[c * 27 + i];
  float bv = bias[c];
  __syncthreads();

  int s   = tid & 7;
  int tc  = (tid >> 3) & 1;
  int seg = tid >> 4;
  int h0 = seg * 4;
  int cb = 3 + 8 * s;

  float win[3][3][10];
#define LOADROW(q, slot, ldsrow) { \
    const float* rp = &lds[(((tc) + (q)) * 66 + (ldsrow)) * 72 + cb]; \
    _Pragma("unroll") for (int j = 0; j < 10; ++j) win[q][slot][j] = rp[j]; }

#pragma unroll
  for (int q = 0; q < 3; ++q) { LOADROW(q, 0, h0); LOADROW(q, 1, h0 + 1); }

  float* yp = y + (size_t)bc * THW + (t0 + tc) * HW + s * 8;
#pragma unroll
  for (int st = 0; st < 4; ++st) {
    int h = h0 + st;
#pragma unroll
    for (int q = 0; q < 3; ++q) { LOADROW(q, (st + 2) % 3, h + 2); }
    float acc[8];
#pragma unroll
    for (int w = 0; w < 8; ++w) acc[w] = bv;
#pragma unroll
    for (int q = 0; q < 3; ++q)
#pragma unroll
      for (int rr = 0; rr < 3; ++rr) {
        const float* row = win[q][(st + rr) % 3];
#pragma unroll
        for (int dw = 0; dw < 3; ++dw) {
          float coef = w27[q * 9 + rr * 3 + dw];
#pragma unroll
          for (int w = 0; w < 8; ++w) acc[w] = fmaf(row[w + dw], coef, acc[w]);
        }
      }
    *(float4*)&yp[h * 64]     = make_float4(acc[0], acc[1], acc[2], acc[3]);
    *(float4*)&yp[h * 64 + 4] = make_float4(acc[4], acc[5], acc[6], acc[7]);
  }
#undef LOADROW
}

// ---------------- fe transpose: [THW][96] -> [96][THW] -----------------------
__global__ __launch_bounds__(256) void feT_k(const float* __restrict__ fe,
                                             float* __restrict__ feT) {
  __shared__ float t[96 * 65];
  int tid = threadIdx.x;
  int tok0 = blockIdx.x * 64;
  const float* p = fe + (size_t)tok0 * 96;
  for (int i = tid; i < 6144; i += 256) {
    int tok = i / 96;
    int ch = i - tok * 96;
    t[ch * 65 + tok] = p[i];
  }
  __syncthreads();
  for (int i = tid; i < 6144; i += 256) {
    int ch = i >> 6, tok = i & 63;
    feT[(size_t)ch * THW + tok0 + tok] = t[ch * 65 + tok];
  }
}

// ---------------- LDS-staged 96xN GEMM family, 512 threads -------------------
// 8 waves x 12 outputs each -> acc[12] = 48 VGPR (cannot spill).
#define FMA4(A, WV) \
  A.x = fmaf(WV, v.x, A.x); A.y = fmaf(WV, v.y, A.y); \
  A.z = fmaf(WV, v.z, A.z); A.w = fmaf(WV, v.w, A.w);

#define WPAD 104
#define BK32 32

template <int EPI>
__global__ __launch_bounds__(512) void gemm96_k(
    const float* __restrict__ In, const float* __restrict__ W,
    const float* __restrict__ bias, float* __restrict__ Out,
    float* __restrict__ Out2, const float* __restrict__ zg,
    const float* __restrict__ lnG, const float* __restrict__ lnB,
    const float* __restrict__ scal_c, const float* __restrict__ scal_a,
    int N, size_t inStride, size_t outStride) {
  __shared__ float Wt[96 * WPAD];      // [k][co], padded (39 KB)
  __shared__ float buf[BK32 * 256];    // 32 KB
  int tid = threadIdx.x;
  int wvi = tid >> 6, ln = tid & 63;   // 8 waves
  for (int i = tid; i < 2304; i += 512) {
    int k4 = i / 96, co = i - k4 * 96;
    float4 w4 = *(const float4*)(W + co * 96 + k4 * 4);
    int k = k4 * 4;
    Wt[(k + 0) * WPAD + co] = w4.x;
    Wt[(k + 1) * WPAD + co] = w4.y;
    Wt[(k + 2) * WPAD + co] = w4.z;
    Wt[(k + 3) * WPAD + co] = w4.w;
  }
  int n0 = blockIdx.x * 256 + ln * 4;
  int co0 = wvi * 12;
  const float* ipb = In + blockIdx.y * inStride + blockIdx.x * 256 + ln * 4;
  const float* zpb = (EPI == 2) ? (zg + blockIdx.y * inStride + blockIdx.x * 256 + ln * 4)
                                : nullptr;

  float4 mu4, rs4;
  if (EPI == 2) {   // per-token LN stats for this lane's 4 tokens
    float4 sum = make_float4(0.f, 0.f, 0.f, 0.f);
    float4 sq  = make_float4(0.f, 0.f, 0.f, 0.f);
#pragma unroll 8
    for (int ci = 0; ci < 96; ++ci) {
      float4 t = *(const float4*)(ipb + (size_t)ci * N);
      sum.x += t.x; sum.y += t.y; sum.z += t.z; sum.w += t.w;
      sq.x = fmaf(t.x, t.x, sq.x); sq.y = fmaf(t.y, t.y, sq.y);
      sq.z = fmaf(t.z, t.z, sq.z); sq.w = fmaf(t.w, t.w, sq.w);
    }
    const float r96 = 1.0f / 96.0f;
    mu4.x = sum.x * r96; mu4.y = sum.y * r96; mu4.z = sum.z * r96; mu4.w = sum.w * r96;
    rs4.x = rsqrtf(fmaxf(sq.x * r96 - mu4.x * mu4.x, 0.f) + 1e-5f);
    rs4.y = rsqrtf(fmaxf(sq.y * r96 - mu4.y * mu4.y, 0.f) + 1e-5f);
    rs4.z = rsqrtf(fmaxf(sq.z * r96 - mu4.z * mu4.z, 0.f) + 1e-5f);
    rs4.w = rsqrtf(fmaxf(sq.w * r96 - mu4.w * mu4.w, 0.f) + 1e-5f);
  }

  float4 acc[12];
#pragma unroll
  for (int j = 0; j < 12; ++j) {
    float bj = bias[co0 + j];
    acc[j] = make_float4(bj, bj, bj, bj);
  }

#pragma unroll 1
  for (int kb = 0; kb < 3; ++kb) {
#pragma unroll
    for (int i = 0; i < 4; ++i) {           // 32 rows by 8 waves
      int r = i * 8 + wvi;
      int k = kb * BK32 + r;
      float4 v4 = *(const float4*)(ipb + (size_t)k * N);
      if (EPI == 2) {
        float4 zz = *(const float4*)(zpb + (size_t)k * N);
        float lgk = lnG[k], lbk = lnB[k];
        float gx = zz.x * __builtin_amdgcn_rcpf(1.0f + __expf(-zz.x));
        float gy = zz.y * __builtin_amdgcn_rcpf(1.0f + __expf(-zz.y));
        float gz = zz.z * __builtin_amdgcn_rcpf(1.0f + __expf(-zz.z));
        float gw = zz.w * __builtin_amdgcn_rcpf(1.0f + __expf(-zz.w));
        v4.x = fmaf((v4.x - mu4.x) * rs4.x, lgk, lbk) * gx;
        v4.y = fmaf((v4.y - mu4.y) * rs4.y, lgk, lbk) * gy;
        v4.z = fmaf((v4.z - mu4.z) * rs4.z, lgk, lbk) * gz;
        v4.w = fmaf((v4.w - mu4.w) * rs4.w, lgk, lbk) * gw;
      }
      *(float4*)&buf[r * 256 + ln * 4] = v4;
    }
    __syncthreads();
#pragma unroll 8
    for (int kk = 0; kk < BK32; ++kk) {
      int k = kb * BK32 + kk;
      float4 v = *(const float4*)&buf[kk * 256 + ln * 4];
      const float4* wr = (const float4*)&Wt[k * WPAD + co0];
#pragma unroll
      for (int j = 0; j < 3; ++j) {
        float4 wvv = wr[j];
        FMA4(acc[4 * j + 0], wvv.x);
        FMA4(acc[4 * j + 1], wvv.y);
        FMA4(acc[4 * j + 2], wvv.z);
        FMA4(acc[4 * j + 3], wvv.w);
      }
    }
    __syncthreads();
  }

  if (EPI == 1) {
    float cv = scal_c[0], al = scal_a[0];
    float rc = 1.0f / (cv + 1e-8f);
#define TAUMAP(T, AA, BB) { \
    float tau = 0.5f * (T) * (1.0f + erff((T) * 0.70710678118654752f)); \
    float ct = cv * tau; \
    float damp = __expf(-0.5f * al * tau); \
    float sc = __sinf(ct), cc = __cosf(ct); \
    AA = damp * (cc + sc * al * 0.5f * rc); BB = damp * sc * rc; }
#pragma unroll 2
    for (int j = 0; j < 12; ++j) {
      float4 a4, b4;
      TAUMAP(acc[j].x, a4.x, b4.x);
      TAUMAP(acc[j].y, a4.y, b4.y);
      TAUMAP(acc[j].z, a4.z, b4.z);
      TAUMAP(acc[j].w, a4.w, b4.w);
      *(float4*)(Out  + (size_t)(co0 + j) * N + n0) = a4;
      *(float4*)(Out2 + (size_t)(co0 + j) * N + n0) = b4;
    }
#undef TAUMAP
  } else {
    float* op = Out + blockIdx.y * outStride + n0;
#pragma unroll
    for (int j = 0; j < 12; ++j)
      *(float4*)(op + (size_t)(co0 + j) * N) = acc[j];
  }
}

// ---------------- fused W+H (I)DCT, 4x4 register-tiled -----------------------
__global__ __launch_bounds__(256) void wh_k(const float* __restrict__ in,
    float* __restrict__ out, const float* __restrict__ basis) {
  __shared__ float XT[64 * 68];
  __shared__ float Yb[64 * 68];
  __shared__ float Bs[64 * 68];
  int tid = threadIdx.x;
  const float* ip = in + (size_t)blockIdx.x * HW;
  float* op = out + (size_t)blockIdx.x * HW;
  for (int i = tid; i < 1024; i += 256) {
    int r = i >> 4, c4 = i & 15;
    float4 v = *(const float4*)(basis + r * 64 + c4 * 4);
    *(float4*)&Bs[r * 68 + c4 * 4] = v;
  }
  for (int i = tid; i < 1024; i += 256) {
    int h = i >> 4, w4 = i & 15;
    float4 v = *(const float4*)(ip + h * 64 + w4 * 4);
    int w = w4 * 4;
    XT[(w + 0) * 68 + h] = v.x;
    XT[(w + 1) * 68 + h] = v.y;
    XT[(w + 2) * 68 + h] = v.z;
    XT[(w + 3) * 68 + h] = v.w;
  }
  __syncthreads();
  int nb = tid & 15, rb = tid >> 4;
  int n0 = nb * 4, r0 = rb * 4;
  {
    float4 a0 = make_float4(0.f, 0.f, 0.f, 0.f), a1 = a0, a2 = a0, a3 = a0;
#pragma unroll 8
    for (int w = 0; w < 64; ++w) {
      float4 xv = *(const float4*)&XT[w * 68 + r0];
      float4 bv = *(const float4*)&Bs[w * 68 + n0];
      a0.x = fmaf(xv.x, bv.x, a0.x); a0.y = fmaf(xv.x, bv.y, a0.y);
      a0.z = fmaf(xv.x, bv.z, a0.z); a0.w = fmaf(xv.x, bv.w, a0.w);
      a1.x = fmaf(xv.y, bv.x, a1.x); a1.y = fmaf(xv.y, bv.y, a1.y);
      a1.z = fmaf(xv.y, bv.z, a1.z); a1.w = fmaf(xv.y, bv.w, a1.w);
      a2.x = fmaf(xv.z, bv.x, a2.x); a2.y = fmaf(xv.z, bv.y, a2.y);
      a2.z = fmaf(xv.z, bv.z, a2.z); a2.w = fmaf(xv.z, bv.w, a2.w);
      a3.x = fmaf(xv.w, bv.x, a3.x); a3.y = fmaf(xv.w, bv.y, a3.y);
      a3.z = fmaf(xv.w, bv.z, a3.z); a3.w = fmaf(xv.w, bv.w, a3.w);
    }
    *(float4*)&Yb[(r0 + 0) * 68 + n0] = a0;
    *(float4*)&Yb[(r0 + 1) * 68 + n0] = a1;
    *(float4*)&Yb[(r0 + 2) * 68 + n0] = a2;
    *(float4*)&Yb[(r0 + 3) * 68 + n0] = a3;
  }
  __syncthreads();
  {
    float4 a0 = make_float4(0.f, 0.f, 0.f, 0.f), a1 = a0, a2 = a0, a3 = a0;
#pragma unroll 8
    for (int h = 0; h < 64; ++h) {
      float4 bv = *(const float4*)&Bs[h * 68 + r0];
      float4 yv = *(const float4*)&Yb[h * 68 + n0];
      a0.x = fmaf(bv.x, yv.x, a0.x); a0.y = fmaf(bv.x, yv.y, a0.y);
      a0.z = fmaf(bv.x, yv.z, a0.z); a0.w = fmaf(bv.x, yv.w, a0.w);
      a1.x = fmaf(bv.y, yv.x, a1.x); a1.y = fmaf(bv.y, yv.y, a1.y);
      a1.z = fmaf(bv.y, yv.z, a1.z); a1.w = fmaf(bv.y, yv.w, a1.w);
      a2.x = fmaf(bv.z, yv.x, a2.x); a2.y = fmaf(bv.z, yv.y, a2.y);
      a2.z = fmaf(bv.z, yv.z, a2.z); a2.w = fmaf(bv.z, yv.w, a2.w);
      a3.x = fmaf(bv.w, yv.x, a3.x); a3.y = fmaf(bv.w, yv.y, a3.y);
      a3.z = fmaf(bv.w, yv.z, a3.z); a3.w = fmaf(bv.w, yv.w, a3.w);
    }
    *(float4*)&op[(r0 + 0) * 64 + n0] = a0;
    *(float4*)&op[(r0 + 1) * 64 + n0] = a1;
    *(float4*)&op[(r0 + 2) * 64 + n0] = a2;
    *(float4*)&op[(r0 + 3) * 64 + n0] = a3;
  }
}

// ---------------- fused T-DCT + spectral multiply + T-IDCT -------------------
// Phase-separated register flow: u -> ua (u dies), v -> va (v dies), so, out.
__global__ __launch_bounds__(256) void tspec_k(const float* __restrict__ U0,
    const float* __restrict__ V0, const float* __restrict__ A,
    const float* __restrict__ Bc, const float* __restrict__ b16,
    float* __restrict__ out) {
  __shared__ float bs[256];
  int tid = threadIdx.x;
  bs[tid] = b16[tid];
  __syncthreads();
  int hw = blockIdx.x * 256 + tid;
  int c = blockIdx.y, b = blockIdx.z;
  size_t base = ((size_t)(b * C96 + c) * 16) * HW + hw;
  int cbase = c * THW + hw;
  float ua[16], va[16];
  {
    float u[16];
#pragma unroll
    for (int t = 0; t < 16; ++t) u[t] = U0[base + t * HW];
#pragma unroll
    for (int n = 0; n < 16; ++n) {
      float s = 0.0f;
#pragma unroll
      for (int t = 0; t < 16; ++t) s = fmaf(bs[n * 16 + t], u[t], s);
      ua[n] = s;
    }
  }
  {
    float v[16];
#pragma unroll
    for (int t = 0; t < 16; ++t) v[t] = V0[base + t * HW];
#pragma unroll
    for (int n = 0; n < 16; ++n) {
      float s = 0.0f;
#pragma unroll
      for (int t = 0; t < 16; ++t) s = fmaf(bs[n * 16 + t], v[t], s);
      va[n] = s;
    }
  }
  float so[16];
#pragma unroll 4
  for (int n = 0; n < 16; ++n)
    so[n] = A[cbase + n * HW] * ua[n] + Bc[cbase + n * HW] * va[n];
#pragma unroll
  for (int t = 0; t < 16; ++t) {
    float s = 0.0f;
#pragma unroll
    for (int n = 0; n < 16; ++n) s = fmaf(so[n], bs[n * 16 + t], s);
    out[base + t * HW] = s;
  }
}

extern "C" void kernel_launch(void* const* d_in, const int* in_sizes, int n_in,
                              void* d_out, int out_size, void* d_ws, size_t ws_size,
                              hipStream_t stream) {
  const float* x    = (const float*)d_in[0];
  const float* fe   = (const float*)d_in[1];
  const float* dww  = (const float*)d_in[2];
  const float* dwb  = (const float*)d_in[3];
  const float* linW = (const float*)d_in[4];
  const float* linB = (const float*)d_in[5];
  const float* v0W  = (const float*)d_in[6];
  const float* v0B  = (const float*)d_in[7];
  const float* tokW = (const float*)d_in[8];
  const float* tokB = (const float*)d_in[9];
  const float* cS   = (const float*)d_in[10];
  const float* aS   = (const float*)d_in[11];
  const float* lnG  = (const float*)d_in[12];
  const float* lnBp = (const float*)d_in[13];
  const float* outW = (const float*)d_in[14];
  const float* outB = (const float*)d_in[15];
  float* out = (float*)d_out;

  float* w = (float*)d_ws;
  const size_t TEN = (size_t)2 * C96 * THW;
  const size_t BST = (size_t)C96 * THW;
  float* b64    = w;                 // 4096
  float* b64T   = w + 4096;          // 4096
  float* b16    = w + 8192;          // 256
  float* buf_y  = w + 16384;
  float* buf_xg = buf_y + TEN;
  float* buf_z  = buf_xg + TEN;
  float* buf_v0 = buf_z + TEN;
  float* bufA   = buf_v0 + TEN;
  float* bufB   = bufA + BST;
  size_t need = (size_t)(16384 + 4 * TEN + 2 * BST) * sizeof(float);
  if (ws_size < need) return;

  hipLaunchKernelGGL(init_basis_k, dim3(1), dim3(256), 0, stream, b64, b64T, b16);
  hipLaunchKernelGGL(dwconv_k, dim3(8, 192), dim3(256), 0, stream, x, dww, dwb, buf_y);
  hipLaunchKernelGGL((gemm96_k<0>), dim3(256, 2), dim3(512), 0, stream,
                     buf_y, linW, linB, buf_xg, (float*)nullptr, (const float*)nullptr,
                     (const float*)nullptr, (const float*)nullptr,
                     (const float*)nullptr, (const float*)nullptr, THW, BST, BST);
  hipLaunchKernelGGL((gemm96_k<0>), dim3(256, 2), dim3(512), 0, stream,
                     buf_y, linW + 9216, linB + 96, buf_z, (float*)nullptr, (const float*)nullptr,
                     (const float*)nullptr, (const float*)nullptr,
                     (const float*)nullptr, (const float*)nullptr, THW, BST, BST);
  hipLaunchKernelGGL(feT_k, dim3(1024), dim3(256), 0, stream, fe, buf_v0);
  hipLaunchKernelGGL((gemm96_k<1>), dim3(256, 1), dim3(512), 0, stream,
                     buf_v0, tokW, tokB, bufA, bufB, (const float*)nullptr,
                     (const float*)nullptr, (const float*)nullptr,
                     cS, aS, THW, (size_t)0, (size_t)0);
  hipLaunchKernelGGL((gemm96_k<0>), dim3(256, 2), dim3(512), 0, stream,
                     buf_xg, v0W, v0B, buf_v0, (float*)nullptr, (const float*)nullptr,
                     (const float*)nullptr, (const float*)nullptr,
                     (const float*)nullptr, (const float*)nullptr, THW, BST, BST);
  hipLaunchKernelGGL(wh_k, dim3(3072), dim3(256), 0, stream, buf_xg, buf_y, b64T);
  hipLaunchKernelGGL(wh_k, dim3(3072), dim3(256), 0, stream, buf_v0, buf_xg, b64T);
  hipLaunchKernelGGL(tspec_k, dim3(16, 96, 2), dim3(256), 0, stream, buf_y, buf_xg, bufA, bufB, b16, buf_v0);
  hipLaunchKernelGGL(wh_k, dim3(3072), dim3(256), 0, stream, buf_v0, buf_y, b64);
  hipLaunchKernelGGL((gemm96_k<2>), dim3(256, 2), dim3(512), 0, stream,
                     buf_y, outW, outB, out, (float*)nullptr, buf_z,
                     lnG, lnBp, (const float*)nullptr, (const float*)nullptr, THW, BST, BST);
}